// Round 6
// baseline (776.906 us; speedup 1.0000x reference)
//
#include <hip/hip_runtime.h>
#include <hip/hip_bf16.h>

#define DM        1024
#define D_INNER   2048
#define NHEADS    32
#define HEADDIM   64
#define DSTATE    128
#define DCONV     4
#define CONV_DIM  (D_INNER + 2*DSTATE)            // 2304
#define D_IN_PROJ (2*D_INNER + 2*DSTATE + NHEADS) // 4384
#define NPAD_IN   4480                            // 35*128, padded N for K1
#define BATCH     4
#define SEQ       1024
#define NROWS     (BATCH*SEQ)                     // 4096
#define EPSF      1e-5f
#define CHUNK     256
#define NCHUNK    (SEQ/CHUNK)                     // 4

// ---------------- workspace layout ----------------
// float region
#define OFF_ZX   ((size_t)0)                        // [4096][4384]  zxbcdt fp32
#define OFF_XBC  ((size_t)(NROWS)*D_IN_PROJ)        // [4096][2304]
#define OFF_DT   (OFF_XBC + (size_t)NROWS*CONV_DIM) // [4096][32]
#define OFF_DA   (OFF_DT  + (size_t)NROWS*NHEADS)   // [4096][32]
#define OFF_Y    (OFF_DA  + (size_t)NROWS*NHEADS)   // [4096][2048] fp32
#define FLOAT_END (OFF_Y + (size_t)NROWS*D_INNER)
// bf16 (short) region, offsets in shorts from (short*)(ws + FLOAT_END)
#define SOFF_XB   ((size_t)0)                           // [4096][1024]   dead after K1
#define SOFF_W1B  (SOFF_XB  + (size_t)NROWS*DM)         // [4480][1024]   dead after K1
#define SOFF_W2B  (SOFF_W1B + (size_t)NPAD_IN*DM)       // [1024][2048]
#define SOFF_YZB  (SOFF_W2B + (size_t)DM*D_INNER)       // [4096][2048]
// h_delta/h_in buffer overlays xb+w1b (17.56 MB region, needs 16.78+0.004 MB),
// used only AFTER K1 finishes. [NCHUNK][256 bh2][4096 states] + datot[NCHUNK][128]
#define HD_FLOATS ((size_t)NCHUNK*256*4096)

typedef float  vf4   __attribute__((ext_vector_type(4)));
typedef short  s16x8 __attribute__((ext_vector_type(8)));
typedef short  s16x4 __attribute__((ext_vector_type(4)));
typedef __bf16 bf16x8 __attribute__((ext_vector_type(8)));

__device__ __forceinline__ float sigmoidf_(float x) { return 1.f / (1.f + expf(-x)); }

__device__ __forceinline__ short f2bf(float f) {
    unsigned u = __builtin_bit_cast(unsigned, f);
    u += 0x7fffu + ((u >> 16) & 1u);          // RNE
    return (short)(u >> 16);
}
__device__ __forceinline__ bf16x8 as_bf(s16x8 v) { return __builtin_bit_cast(bf16x8, v); }

__device__ __forceinline__ void gload16(const short* g, short* l) {
    __builtin_amdgcn_global_load_lds(
        (const __attribute__((address_space(1))) unsigned int*)g,
        (__attribute__((address_space(3))) unsigned int*)l, 16, 0, 0);
}

// ---------------- K0: fp32 -> bf16 convert (optionally zero-padded tail) ----
__global__ __launch_bounds__(256) void cvt_bf16(const float* __restrict__ src,
                                                short* __restrict__ dst,
                                                int n_src, int n_dst) {
    int i = (blockIdx.x * 256 + threadIdx.x) * 4;
    if (i >= n_dst) return;
    s16x4 o;
    if (i + 3 < n_src) {
        float4 v = *(const float4*)(src + i);
        o[0] = f2bf(v.x); o[1] = f2bf(v.y); o[2] = f2bf(v.z); o[3] = f2bf(v.w);
    } else {
        #pragma unroll
        for (int j = 0; j < 4; ++j) o[j] = (i + j < n_src) ? f2bf(src[i + j]) : (short)0;
    }
    *(s16x4*)(dst + i) = o;
}

// ---------------- MFMA GEMM: C[M][Nout] = A[M][K] * B[Npad][K]^T ------------
__global__ __launch_bounds__(256) void gemm_mfma(const short* __restrict__ A,
                                                 const short* __restrict__ B,
                                                 float* __restrict__ C,
                                                 int M, int K, int Nout) {
    __shared__ short smem[16384];               // A:[0,8192) B:[8192,16384) shorts
    const int tid = threadIdx.x;
    const int bm = blockIdx.y * 128, bn = blockIdx.x * 128;
    const int lane = tid & 63, lr = lane & 15, lg = lane >> 4;
    const int w = tid >> 6, wm = w >> 1, wn = w & 1;

    const short* ga[4]; const short* gb[4];
    short* la[4]; short* lb[4];
    #pragma unroll
    for (int t = 0; t < 4; ++t) {
        int s = t * 256 + tid;                  // slot 0..1023
        int r = s >> 3;
        int c = (s & 7) ^ (r & 7);              // pre-swizzled source chunk
        ga[t] = A + (size_t)(bm + r) * K + c * 8;
        gb[t] = B + (size_t)(bn + r) * K + c * 8;
        la[t] = &smem[s * 8];
        lb[t] = &smem[8192 + s * 8];
    }

    vf4 acc[4][4] = {};

    for (int k0 = 0; k0 < K; k0 += 64) {
        __syncthreads();
        #pragma unroll
        for (int t = 0; t < 4; ++t) gload16(ga[t] + k0, la[t]);
        #pragma unroll
        for (int t = 0; t < 4; ++t) gload16(gb[t] + k0, lb[t]);
        __syncthreads();
        #pragma unroll
        for (int kk = 0; kk < 2; ++kk) {
            const int co = ((kk * 4 + lg) ^ (lr & 7)) * 8;
            s16x8 av[4], bv[4];
            #pragma unroll
            for (int f = 0; f < 4; ++f) {
                av[f] = *(const s16x8*)&smem[(wm * 64 + f * 16 + lr) * 64 + co];
                bv[f] = *(const s16x8*)&smem[8192 + (wn * 64 + f * 16 + lr) * 64 + co];
            }
            #pragma unroll
            for (int i = 0; i < 4; ++i)
                #pragma unroll
                for (int j = 0; j < 4; ++j)
                    acc[i][j] = __builtin_amdgcn_mfma_f32_16x16x32_bf16(
                        as_bf(av[i]), as_bf(bv[j]), acc[i][j], 0, 0, 0);
        }
    }

    #pragma unroll
    for (int i = 0; i < 4; ++i) {
        int row = bm + wm * 64 + i * 16 + lg * 4;
        #pragma unroll
        for (int j = 0; j < 4; ++j) {
            int col = bn + wn * 64 + j * 16 + lr;
            if (col < Nout) {
                float* cp = C + (size_t)row * Nout + col;
                #pragma unroll
                for (int q = 0; q < 4; ++q) cp[(size_t)q * Nout] = acc[i][j][q];
            }
        }
    }
}

// ---------------- K2: causal depthwise conv(4) + silu ----------------
__global__ __launch_bounds__(256) void conv_silu(const float* __restrict__ zx,
                                                 const float* __restrict__ cw,
                                                 const float* __restrict__ cb,
                                                 float* __restrict__ xBC) {
    int idx = blockIdx.x * 256 + threadIdx.x;
    if (idx >= NROWS * CONV_DIM) return;
    int c  = idx % CONV_DIM;
    int bl = idx / CONV_DIM;
    int b  = bl / SEQ;
    int l  = bl % SEQ;

    float w0 = cw[c*4+0], w1 = cw[c*4+1], w2 = cw[c*4+2], w3 = cw[c*4+3];
    const float* base = zx + (size_t)b * SEQ * D_IN_PROJ + D_INNER + c;

    float acc = cb[c];
    if (l >= 3) acc = fmaf(base[(size_t)(l-3) * D_IN_PROJ], w0, acc);
    if (l >= 2) acc = fmaf(base[(size_t)(l-2) * D_IN_PROJ], w1, acc);
    if (l >= 1) acc = fmaf(base[(size_t)(l-1) * D_IN_PROJ], w2, acc);
    acc = fmaf(base[(size_t)l * D_IN_PROJ], w3, acc);

    xBC[idx] = acc * sigmoidf_(acc);
}

// ---------------- K2b: dt = softplus(dt_raw + bias), dA = exp(dt*A) ---------
__global__ __launch_bounds__(256) void dt_da(const float* __restrict__ zx,
                                             const float* __restrict__ dt_bias,
                                             const float* __restrict__ A_log,
                                             float* __restrict__ dt,
                                             float* __restrict__ dA) {
    int idx = blockIdx.x * 256 + threadIdx.x;
    if (idx >= NROWS * NHEADS) return;
    int h  = idx & (NHEADS - 1);
    int bl = idx >> 5;
    float u = zx[(size_t)bl * D_IN_PROJ + D_INNER + CONV_DIM + h] + dt_bias[h];
    float d = (u > 20.f) ? u : log1pf(expf(u));
    dt[idx] = d;
    dA[idx] = expf(-expf(A_log[h]) * d);
}

// ---------------- K3: chunked SSM scan ----------------
// Split L into NCHUNK chunks of CHUNK. h_t = h_delta_t + (prod dA)*h_in; exact.
// Pass A: per-chunk scan with h_in = 0; writes y_intra(+D*x), h_delta, dA_total.
// Pass B: combine chunk states sequentially (4 steps, in-register).
// Pass C: y += cumprod_t * (C_t . h_in[chunk]).
// Block decode (A/C): grid = B*H*2*NCHUNK = 1024.
// Thread: p_loc = tid>>4 (0..31), nseg = tid&15 -> 8 states n0 = nseg*8.

struct ScanVals { float4 b0, b1, c0, c1; float xv, dtv, dAv; };

__device__ __forceinline__ void scan_load(const float* __restrict__ row,
                                          const float* __restrict__ dtp,
                                          const float* __restrict__ dAp,
                                          int hoff, int n0, ScanVals& v) {
    v.b0 = *(const float4*)(row + D_INNER + n0);
    v.b1 = *(const float4*)(row + D_INNER + n0 + 4);
    v.c0 = *(const float4*)(row + D_INNER + DSTATE + n0);
    v.c1 = *(const float4*)(row + D_INNER + DSTATE + n0 + 4);
    v.xv  = row[hoff];
    v.dtv = *dtp;
    v.dAv = *dAp;
}

__global__ __launch_bounds__(512) void ssm_chunk_a(const float* __restrict__ xBC,
                                                   const float* __restrict__ dt,
                                                   const float* __restrict__ dA,
                                                   const float* __restrict__ Dp,
                                                   float* __restrict__ y,
                                                   float* __restrict__ hd,
                                                   float* __restrict__ datot) {
    int blk = blockIdx.x;           // 0..1023
    int k   = blk & (NCHUNK - 1);
    int pch = (blk >> 2) & 1;
    int h   = (blk >> 3) & (NHEADS - 1);
    int b   = blk >> 8;

    int t     = threadIdx.x;
    int p_loc = t >> 4;
    int nseg  = t & 15;
    int n0    = nseg * 8;
    int p     = pch * 32 + p_loc;
    int hoff  = h * HEADDIM + p;
    int l0    = k * CHUNK;

    float hs[8];
    #pragma unroll
    for (int i = 0; i < 8; ++i) hs[i] = 0.f;
    float prod = 1.f;

    float Dh = Dp[h];
    const float* xbase = xBC + ((size_t)b * SEQ + l0) * CONV_DIM;
    const float* dtb   = dt + ((size_t)b * SEQ + l0) * NHEADS + h;
    const float* dAb   = dA + ((size_t)b * SEQ + l0) * NHEADS + h;
    float*       yb    = y + ((size_t)b * SEQ + l0) * D_INNER + hoff;

    ScanVals vA, vB;
    scan_load(xbase, dtb, dAb, hoff, n0, vA);

    #define SCAN_STEP(V, L)                                                        \
    {                                                                              \
        float dtx = V.dtv * V.xv;                                                  \
        float partial = 0.f;                                                       \
        hs[0] = fmaf(V.dAv, hs[0], dtx * V.b0.x); partial = fmaf(hs[0], V.c0.x, partial); \
        hs[1] = fmaf(V.dAv, hs[1], dtx * V.b0.y); partial = fmaf(hs[1], V.c0.y, partial); \
        hs[2] = fmaf(V.dAv, hs[2], dtx * V.b0.z); partial = fmaf(hs[2], V.c0.z, partial); \
        hs[3] = fmaf(V.dAv, hs[3], dtx * V.b0.w); partial = fmaf(hs[3], V.c0.w, partial); \
        hs[4] = fmaf(V.dAv, hs[4], dtx * V.b1.x); partial = fmaf(hs[4], V.c1.x, partial); \
        hs[5] = fmaf(V.dAv, hs[5], dtx * V.b1.y); partial = fmaf(hs[5], V.c1.y, partial); \
        hs[6] = fmaf(V.dAv, hs[6], dtx * V.b1.z); partial = fmaf(hs[6], V.c1.z, partial); \
        hs[7] = fmaf(V.dAv, hs[7], dtx * V.b1.w); partial = fmaf(hs[7], V.c1.w, partial); \
        prod *= V.dAv;                                                             \
        partial += __shfl_xor(partial, 1);                                         \
        partial += __shfl_xor(partial, 2);                                         \
        partial += __shfl_xor(partial, 4);                                         \
        partial += __shfl_xor(partial, 8);                                         \
        if (nseg == 0) yb[(size_t)(L) * D_INNER] = fmaf(Dh, V.xv, partial);        \
    }

    for (int l = 0; l < CHUNK; l += 2) {
        int l1 = l + 1;
        scan_load(xbase + (size_t)l1 * CONV_DIM, dtb + (size_t)l1 * NHEADS,
                  dAb + (size_t)l1 * NHEADS, hoff, n0, vB);
        SCAN_STEP(vA, l);
        int l2 = (l + 2 < CHUNK) ? l + 2 : CHUNK - 1;   // redundant tail load
        scan_load(xbase + (size_t)l2 * CONV_DIM, dtb + (size_t)l2 * NHEADS,
                  dAb + (size_t)l2 * NHEADS, hoff, n0, vA);
        SCAN_STEP(vB, l1);
    }
    #undef SCAN_STEP

    int bh2 = ((b * NHEADS + h) * 2 + pch);
    size_t off = ((size_t)k * 256 + bh2) * 4096 + p_loc * 128 + n0;
    *(float4*)&hd[off]     = make_float4(hs[0], hs[1], hs[2], hs[3]);
    *(float4*)&hd[off + 4] = make_float4(hs[4], hs[5], hs[6], hs[7]);
    if (t == 0) datot[k * (BATCH * NHEADS) + b * NHEADS + h] = prod;
}

// Pass B: in-place h_delta -> h_in. grid 256 (bh2), 512 threads, 8 states each.
__global__ __launch_bounds__(512) void ssm_chunk_b(float* __restrict__ hd,
                                                   const float* __restrict__ datot) {
    int bh2 = blockIdx.x;
    int bh  = bh2 >> 1;
    size_t base = (size_t)bh2 * 4096 + threadIdx.x * 8;

    float h[8];
    #pragma unroll
    for (int i = 0; i < 8; ++i) h[i] = 0.f;

    #pragma unroll
    for (int k = 0; k < NCHUNK; ++k) {
        size_t off = (size_t)k * 256 * 4096 + base;
        float da = datot[k * (BATCH * NHEADS) + bh];
        float4 d0 = *(const float4*)&hd[off];
        float4 d1 = *(const float4*)&hd[off + 4];
        *(float4*)&hd[off]     = make_float4(h[0], h[1], h[2], h[3]);  // h_in[k]
        *(float4*)&hd[off + 4] = make_float4(h[4], h[5], h[6], h[7]);
        h[0] = fmaf(da, h[0], d0.x); h[1] = fmaf(da, h[1], d0.y);
        h[2] = fmaf(da, h[2], d0.z); h[3] = fmaf(da, h[3], d0.w);
        h[4] = fmaf(da, h[4], d1.x); h[5] = fmaf(da, h[5], d1.y);
        h[6] = fmaf(da, h[6], d1.z); h[7] = fmaf(da, h[7], d1.w);
    }
}

// Pass C: y += cumprod_t * (C_t . h_in).  Same decode as A; k==0 exits.
struct CVals { float4 c0, c1; float dAv; };

__device__ __forceinline__ void c_load(const float* __restrict__ row,
                                       const float* __restrict__ dAp,
                                       int n0, CVals& v) {
    v.c0 = *(const float4*)(row + D_INNER + DSTATE + n0);
    v.c1 = *(const float4*)(row + D_INNER + DSTATE + n0 + 4);
    v.dAv = *dAp;
}

__global__ __launch_bounds__(512) void ssm_chunk_c(const float* __restrict__ xBC,
                                                   const float* __restrict__ dA,
                                                   const float* __restrict__ hd,
                                                   float* __restrict__ y) {
    int blk = blockIdx.x;
    int k   = blk & (NCHUNK - 1);
    if (k == 0) return;
    int pch = (blk >> 2) & 1;
    int h   = (blk >> 3) & (NHEADS - 1);
    int b   = blk >> 8;

    int t     = threadIdx.x;
    int p_loc = t >> 4;
    int nseg  = t & 15;
    int n0    = nseg * 8;
    int p     = pch * 32 + p_loc;
    int hoff  = h * HEADDIM + p;
    int l0    = k * CHUNK;

    int bh2 = ((b * NHEADS + h) * 2 + pch);
    size_t off = ((size_t)k * 256 + bh2) * 4096 + p_loc * 128 + n0;
    float4 h0 = *(const float4*)&hd[off];
    float4 h1 = *(const float4*)&hd[off + 4];

    const float* xbase = xBC + ((size_t)b * SEQ + l0) * CONV_DIM;
    const float* dAb   = dA + ((size_t)b * SEQ + l0) * NHEADS + h;
    float*       yb    = y + ((size_t)b * SEQ + l0) * D_INNER + hoff;

    float prod = 1.f;
    CVals vA, vB;
    c_load(xbase, dAb, n0, vA);

    #define C_STEP(V, L)                                                     \
    {                                                                        \
        prod *= V.dAv;                                                       \
        float partial = 0.f;                                                 \
        partial = fmaf(h0.x, V.c0.x, partial); partial = fmaf(h0.y, V.c0.y, partial); \
        partial = fmaf(h0.z, V.c0.z, partial); partial = fmaf(h0.w, V.c0.w, partial); \
        partial = fmaf(h1.x, V.c1.x, partial); partial = fmaf(h1.y, V.c1.y, partial); \
        partial = fmaf(h1.z, V.c1.z, partial); partial = fmaf(h1.w, V.c1.w, partial); \
        partial += __shfl_xor(partial, 1);                                   \
        partial += __shfl_xor(partial, 2);                                   \
        partial += __shfl_xor(partial, 4);                                   \
        partial += __shfl_xor(partial, 8);                                   \
        if (nseg == 0) { float* yp = yb + (size_t)(L) * D_INNER; *yp = fmaf(prod, partial, *yp); } \
    }

    for (int l = 0; l < CHUNK; l += 2) {
        int l1 = l + 1;
        c_load(xbase + (size_t)l1 * CONV_DIM, dAb + (size_t)l1 * NHEADS, n0, vB);
        C_STEP(vA, l);
        int l2 = (l + 2 < CHUNK) ? l + 2 : CHUNK - 1;
        c_load(xbase + (size_t)l2 * CONV_DIM, dAb + (size_t)l2 * NHEADS, n0, vA);
        C_STEP(vB, l1);
    }
    #undef C_STEP
}

// ---------------- K4: yz = y*silu(z); RMSNorm(yz)*norm_w -> bf16 ------------
__global__ __launch_bounds__(256) void gate_rmsnorm(const float* __restrict__ y,
                                                    const float* __restrict__ zx,
                                                    const float* __restrict__ nw,
                                                    short* __restrict__ yzb) {
    int bl = blockIdx.x;
    const float* yr = y + (size_t)bl * D_INNER;
    const float* zr = zx + (size_t)bl * D_IN_PROJ;   // z = first 2048 cols
    int e0 = threadIdx.x * 8;

    float4 y0 = *(const float4*)(yr + e0);
    float4 y1 = *(const float4*)(yr + e0 + 4);
    float4 z0 = *(const float4*)(zr + e0);
    float4 z1 = *(const float4*)(zr + e0 + 4);

    float v[8];
    float zz[8] = {z0.x, z0.y, z0.z, z0.w, z1.x, z1.y, z1.z, z1.w};
    float yy[8] = {y0.x, y0.y, y0.z, y0.w, y1.x, y1.y, y1.z, y1.w};
    float ss = 0.f;
    #pragma unroll
    for (int i = 0; i < 8; ++i) {
        v[i] = yy[i] * zz[i] * sigmoidf_(zz[i]);
        ss = fmaf(v[i], v[i], ss);
    }
    ss += __shfl_xor(ss, 1);  ss += __shfl_xor(ss, 2);  ss += __shfl_xor(ss, 4);
    ss += __shfl_xor(ss, 8);  ss += __shfl_xor(ss, 16); ss += __shfl_xor(ss, 32);
    __shared__ float red[4];
    int wave = threadIdx.x >> 6;
    if ((threadIdx.x & 63) == 0) red[wave] = ss;
    __syncthreads();
    ss = red[0] + red[1] + red[2] + red[3];

    float scale = rsqrtf(ss * (1.f / D_INNER) + EPSF);
    s16x8 o;
    #pragma unroll
    for (int i = 0; i < 8; ++i) o[i] = f2bf(v[i] * scale * nw[e0 + i]);
    *(s16x8*)(yzb + (size_t)bl * D_INNER + e0) = o;
}

// ---------------- launcher ----------------
extern "C" void kernel_launch(void* const* d_in, const int* in_sizes, int n_in,
                              void* d_out, int out_size, void* d_ws, size_t ws_size,
                              hipStream_t stream) {
    const float* x        = (const float*)d_in[0];
    const float* in_w     = (const float*)d_in[1];
    const float* conv_w   = (const float*)d_in[2];
    const float* conv_b   = (const float*)d_in[3];
    const float* dt_bias  = (const float*)d_in[4];
    const float* A_log    = (const float*)d_in[5];
    const float* Dp       = (const float*)d_in[6];
    const float* norm_w   = (const float*)d_in[7];
    const float* out_w    = (const float*)d_in[8];
    float* out            = (float*)d_out;           // fp32 output

    float* ws   = (float*)d_ws;
    float* zx   = ws + OFF_ZX;
    float* xBC  = ws + OFF_XBC;
    float* dt   = ws + OFF_DT;
    float* dA   = ws + OFF_DA;
    float* y    = ws + OFF_Y;
    short* sb   = (short*)(ws + FLOAT_END);
    short* xb   = sb + SOFF_XB;
    short* w1b  = sb + SOFF_W1B;
    short* w2b  = sb + SOFF_W2B;
    short* yzb  = sb + SOFF_YZB;
    float* hd    = (float*)xb;                       // overlays xb+w1b, post-K1
    float* datot = hd + HD_FLOATS;

    // K0: fp32 -> bf16 conversions
    {
        int n = NROWS * DM;
        cvt_bf16<<<n / 4 / 256, 256, 0, stream>>>(x, xb, n, n);
        int ns = D_IN_PROJ * DM, nd = NPAD_IN * DM;
        cvt_bf16<<<nd / 4 / 256, 256, 0, stream>>>(in_w, w1b, ns, nd);
        int n2 = DM * D_INNER;
        cvt_bf16<<<n2 / 4 / 256, 256, 0, stream>>>(out_w, w2b, n2, n2);
    }
    // K1: zxbcdt = x @ in_proj_w^T  (4096 x 4384 x 1024), MFMA bf16
    {
        dim3 grid(NPAD_IN / 128, NROWS / 128);
        gemm_mfma<<<grid, 256, 0, stream>>>(xb, w1b, zx, NROWS, DM, D_IN_PROJ);
    }
    // K2: conv + silu
    {
        int total = NROWS * CONV_DIM;
        conv_silu<<<(total + 255) / 256, 256, 0, stream>>>(zx, conv_w, conv_b, xBC);
    }
    // K2b: dt / dA
    {
        int total = NROWS * NHEADS;
        dt_da<<<(total + 255) / 256, 256, 0, stream>>>(zx, dt_bias, A_log, dt, dA);
    }
    // K3: chunked scan, 3 passes
    ssm_chunk_a<<<BATCH * NHEADS * 2 * NCHUNK, 512, 0, stream>>>(xBC, dt, dA, Dp, y, hd, datot);
    ssm_chunk_b<<<BATCH * NHEADS * 2, 512, 0, stream>>>(hd, datot);
    ssm_chunk_c<<<BATCH * NHEADS * 2 * NCHUNK, 512, 0, stream>>>(xBC, dA, hd, y);
    // K4: gate + rmsnorm -> bf16
    gate_rmsnorm<<<NROWS, 256, 0, stream>>>(y, zx, norm_w, yzb);
    // K5: out = yz @ out_proj_w^T  (4096 x 1024 x 2048), MFMA bf16
    {
        dim3 grid(DM / 128, NROWS / 128);
        gemm_mfma<<<grid, 256, 0, stream>>>(yzb, w2b, out, NROWS, D_INNER, DM);
    }
}

// Round 7
// 364.310 us; speedup vs baseline: 2.1325x; 2.1325x over previous
//
#include <hip/hip_runtime.h>
#include <hip/hip_bf16.h>

#define DM        1024
#define D_INNER   2048
#define NHEADS    32
#define HEADDIM   64
#define DSTATE    128
#define DCONV     4
#define CONV_DIM  (D_INNER + 2*DSTATE)            // 2304
#define D_IN_PROJ (2*D_INNER + 2*DSTATE + NHEADS) // 4384
#define NPAD_IN   4480                            // 35*128, padded N for K1
#define BATCH     4
#define SEQ       1024
#define NROWS     (BATCH*SEQ)                     // 4096
#define EPSF      1e-5f
#define CHUNK     128
#define NCHUNK    (SEQ/CHUNK)                     // 8
#define BH        (BATCH*NHEADS)                  // 128

// ---------------- workspace layout ----------------
#define OFF_ZX   ((size_t)0)                        // [4096][4384]  zxbcdt fp32
#define OFF_XBC  ((size_t)(NROWS)*D_IN_PROJ)        // [4096][2304]
#define OFF_DT   (OFF_XBC + (size_t)NROWS*CONV_DIM) // [4096][32]
#define OFF_DA   (OFF_DT  + (size_t)NROWS*NHEADS)   // [4096][32]
#define OFF_Y    (OFF_DA  + (size_t)NROWS*NHEADS)   // [4096][2048] fp32
#define FLOAT_END (OFF_Y + (size_t)NROWS*D_INNER)
// bf16 (short) region
#define SOFF_XB   ((size_t)0)                           // [4096][1024]  dead after K1
#define SOFF_W1B  (SOFF_XB  + (size_t)NROWS*DM)         // [4480][1024]  dead after K1
#define SOFF_W2B  (SOFF_W1B + (size_t)NPAD_IN*DM)       // [1024][2048]
#define SOFF_YZB  (SOFF_W2B + (size_t)DM*D_INNER)       // [4096][2048]
// h_delta/h_in overlay on xb+w1b (17.56MB avail): [NCHUNK][BH][64p][128n] bf16
// = 16.78MB, + datot [NCHUNK][BH] f32 = 4KB. Used only AFTER K1.
#define HD_SHORTS ((size_t)NCHUNK*BH*HEADDIM*DSTATE)

typedef float  vf4   __attribute__((ext_vector_type(4)));
typedef short  s16x8 __attribute__((ext_vector_type(8)));
typedef short  s16x4 __attribute__((ext_vector_type(4)));
typedef __bf16 bf16x8 __attribute__((ext_vector_type(8)));

__device__ __forceinline__ float sigmoidf_(float x) { return 1.f / (1.f + expf(-x)); }

__device__ __forceinline__ short f2bf(float f) {
    unsigned u = __builtin_bit_cast(unsigned, f);
    u += 0x7fffu + ((u >> 16) & 1u);          // RNE
    return (short)(u >> 16);
}
__device__ __forceinline__ float bf2f(short s) {
    unsigned u = ((unsigned)(unsigned short)s) << 16;
    return __builtin_bit_cast(float, u);
}
__device__ __forceinline__ bf16x8 as_bf(s16x8 v) { return __builtin_bit_cast(bf16x8, v); }
#define MFMA(a,b,c) __builtin_amdgcn_mfma_f32_16x16x32_bf16(as_bf(a), as_bf(b), (c), 0, 0, 0)

__device__ __forceinline__ void gload16(const short* g, short* l) {
    __builtin_amdgcn_global_load_lds(
        (const __attribute__((address_space(1))) unsigned int*)g,
        (__attribute__((address_space(3))) unsigned int*)l, 16, 0, 0);
}

// swizzled [rows][128] bf16 tile: 16B chunk c of row r stored at chunk (c ^ (r&7))
__device__ __forceinline__ int swz_idx(int r, int kc) {
    return r * 128 + (((kc) ^ (r & 7)) << 3);
}
// stage [rows][128] f32 global tile -> swizzled bf16 LDS tile
__device__ __forceinline__ void stage_tile(const float* __restrict__ g, int gstride,
                                           short* __restrict__ lds, int rows, int tid) {
    for (int s = tid; s < rows * 16; s += 512) {
        int r = s >> 4, c = s & 15;
        const float* p = g + (size_t)r * gstride + c * 8;
        float4 v0 = *(const float4*)p, v1 = *(const float4*)(p + 4);
        s16x8 o;
        o[0]=f2bf(v0.x); o[1]=f2bf(v0.y); o[2]=f2bf(v0.z); o[3]=f2bf(v0.w);
        o[4]=f2bf(v1.x); o[5]=f2bf(v1.y); o[6]=f2bf(v1.z); o[7]=f2bf(v1.w);
        *(s16x8*)&lds[swz_idx(r, c)] = o;
    }
}

// ---------------- K0: fp32 -> bf16 convert ----------------
__global__ __launch_bounds__(256) void cvt_bf16(const float* __restrict__ src,
                                                short* __restrict__ dst,
                                                int n_src, int n_dst) {
    int i = (blockIdx.x * 256 + threadIdx.x) * 4;
    if (i >= n_dst) return;
    s16x4 o;
    if (i + 3 < n_src) {
        float4 v = *(const float4*)(src + i);
        o[0] = f2bf(v.x); o[1] = f2bf(v.y); o[2] = f2bf(v.z); o[3] = f2bf(v.w);
    } else {
        #pragma unroll
        for (int j = 0; j < 4; ++j) o[j] = (i + j < n_src) ? f2bf(src[i + j]) : (short)0;
    }
    *(s16x4*)(dst + i) = o;
}

// ---------------- MFMA GEMM (unchanged, proven) ----------------
__global__ __launch_bounds__(256) void gemm_mfma(const short* __restrict__ A,
                                                 const short* __restrict__ B,
                                                 float* __restrict__ C,
                                                 int M, int K, int Nout) {
    __shared__ short smem[16384];
    const int tid = threadIdx.x;
    const int bm = blockIdx.y * 128, bn = blockIdx.x * 128;
    const int lane = tid & 63, lr = lane & 15, lg = lane >> 4;
    const int w = tid >> 6, wm = w >> 1, wn = w & 1;

    const short* ga[4]; const short* gb[4];
    short* la[4]; short* lb[4];
    #pragma unroll
    for (int t = 0; t < 4; ++t) {
        int s = t * 256 + tid;
        int r = s >> 3;
        int c = (s & 7) ^ (r & 7);
        ga[t] = A + (size_t)(bm + r) * K + c * 8;
        gb[t] = B + (size_t)(bn + r) * K + c * 8;
        la[t] = &smem[s * 8];
        lb[t] = &smem[8192 + s * 8];
    }

    vf4 acc[4][4] = {};

    for (int k0 = 0; k0 < K; k0 += 64) {
        __syncthreads();
        #pragma unroll
        for (int t = 0; t < 4; ++t) gload16(ga[t] + k0, la[t]);
        #pragma unroll
        for (int t = 0; t < 4; ++t) gload16(gb[t] + k0, lb[t]);
        __syncthreads();
        #pragma unroll
        for (int kk = 0; kk < 2; ++kk) {
            const int co = ((kk * 4 + lg) ^ (lr & 7)) * 8;
            s16x8 av[4], bv[4];
            #pragma unroll
            for (int f = 0; f < 4; ++f) {
                av[f] = *(const s16x8*)&smem[(wm * 64 + f * 16 + lr) * 64 + co];
                bv[f] = *(const s16x8*)&smem[8192 + (wn * 64 + f * 16 + lr) * 64 + co];
            }
            #pragma unroll
            for (int i = 0; i < 4; ++i)
                #pragma unroll
                for (int j = 0; j < 4; ++j)
                    acc[i][j] = MFMA(av[i], bv[j], acc[i][j]);
        }
    }

    #pragma unroll
    for (int i = 0; i < 4; ++i) {
        int row = bm + wm * 64 + i * 16 + lg * 4;
        #pragma unroll
        for (int j = 0; j < 4; ++j) {
            int col = bn + wn * 64 + j * 16 + lr;
            if (col < Nout) {
                float* cp = C + (size_t)row * Nout + col;
                #pragma unroll
                for (int q = 0; q < 4; ++q) cp[(size_t)q * Nout] = acc[i][j][q];
            }
        }
    }
}

// ---------------- K2: causal depthwise conv(4) + silu ----------------
__global__ __launch_bounds__(256) void conv_silu(const float* __restrict__ zx,
                                                 const float* __restrict__ cw,
                                                 const float* __restrict__ cb,
                                                 float* __restrict__ xBC) {
    int idx = blockIdx.x * 256 + threadIdx.x;
    if (idx >= NROWS * CONV_DIM) return;
    int c  = idx % CONV_DIM;
    int bl = idx / CONV_DIM;
    int b  = bl / SEQ;
    int l  = bl % SEQ;

    float w0 = cw[c*4+0], w1 = cw[c*4+1], w2 = cw[c*4+2], w3 = cw[c*4+3];
    const float* base = zx + (size_t)b * SEQ * D_IN_PROJ + D_INNER + c;

    float acc = cb[c];
    if (l >= 3) acc = fmaf(base[(size_t)(l-3) * D_IN_PROJ], w0, acc);
    if (l >= 2) acc = fmaf(base[(size_t)(l-2) * D_IN_PROJ], w1, acc);
    if (l >= 1) acc = fmaf(base[(size_t)(l-1) * D_IN_PROJ], w2, acc);
    acc = fmaf(base[(size_t)l * D_IN_PROJ], w3, acc);

    xBC[idx] = acc * sigmoidf_(acc);
}

// ---------------- K2b: dt = softplus(dt_raw + bias) ----------------
__global__ __launch_bounds__(256) void dt_da(const float* __restrict__ zx,
                                             const float* __restrict__ dt_bias,
                                             float* __restrict__ dt) {
    int idx = blockIdx.x * 256 + threadIdx.x;
    if (idx >= NROWS * NHEADS) return;
    int h  = idx & (NHEADS - 1);
    int bl = idx >> 5;
    float u = zx[(size_t)bl * D_IN_PROJ + D_INNER + CONV_DIM + h] + dt_bias[h];
    float d = (u > 20.f) ? u : log1pf(expf(u));
    dt[idx] = d;
}

// ---------------- K3a: chunked MFMA scan, intra-chunk ----------------
// grid = B*NCHUNK*NHEADS = 1024, 512 threads. Per block (b,k,h):
//  G = C @ B^T; M = mask(G)*exp(lc_t - lc_j); Y_intra = M @ dtx; h_delta = dtx^T @ Bw.
// LDS tiles (swizzled, [row][128] bf16): CT, BT(->M), BW, XT.
#define L_CT 0
#define L_BT 16384
#define L_BW 32768
#define L_XT 49152
__global__ __launch_bounds__(512) void ssm_mfma_a(const float* __restrict__ xBC,
                                                  const float* __restrict__ dt,
                                                  const float* __restrict__ A_log,
                                                  const float* __restrict__ Dp,
                                                  float* __restrict__ y,
                                                  short* __restrict__ hd16,
                                                  float* __restrict__ datot) {
    __shared__ short sm[57344];
    __shared__ float dtl[128], lcs[128];
    int blk = blockIdx.x;
    int h = blk & 31, k = (blk >> 5) & (NCHUNK - 1), b = blk >> 8;
    int tid = threadIdx.x, w = tid >> 6, lane = tid & 63, lr = lane & 15, lg = lane >> 4;
    int bl0 = b * SEQ + k * CHUNK;
    const float* xrow = xBC + (size_t)bl0 * CONV_DIM;

    // P0: dt slice
    if (tid < 128) dtl[tid] = dt[(size_t)(bl0 + tid) * NHEADS + h];
    __syncthreads();

    // P1: stage C, B, XT(=dt*x transposed [p][t])
    stage_tile(xrow + D_INNER + DSTATE, CONV_DIM, sm + L_CT, 128, tid);  // C
    stage_tile(xrow + D_INNER,          CONV_DIM, sm + L_BT, 128, tid);  // B
    for (int s = tid; s < 64 * 16; s += 512) {
        int p = s >> 4, jc = s & 15;
        s16x8 o;
        #pragma unroll
        for (int jj = 0; jj < 8; ++jj) {
            int j = jc * 8 + jj;
            o[jj] = f2bf(dtl[j] * xrow[(size_t)j * CONV_DIM + h * HEADDIM + p]);
        }
        *(s16x8*)&sm[L_XT + swz_idx(p, jc)] = o;
    }
    __syncthreads();

    // P2: lc = A * inclusive-cumsum(dt), by wave 0
    float Ah = -__expf(A_log[h]);
    if (w == 0) {
        float a = dtl[lane], bb = dtl[64 + lane];
        #pragma unroll
        for (int d = 1; d < 64; d <<= 1) { float v = __shfl_up(a, d);  if (lane >= d) a  += v; }
        #pragma unroll
        for (int d = 1; d < 64; d <<= 1) { float v = __shfl_up(bb, d); if (lane >= d) bb += v; }
        bb += __shfl(a, 63);
        lcs[lane]      = Ah * a;
        lcs[64 + lane] = Ah * bb;
        if (lane == 63) datot[k * BH + b * NHEADS + h] = __expf(Ah * bb);
    }
    __syncthreads();
    float lcLast = lcs[127];

    // P3: build BW[n][j] = B[j][n]*exp(lcLast-lc_j)  +  G = C @ B^T
    for (int s = tid; s < 128 * 16; s += 512) {
        int n = s >> 4, jc = s & 15;
        s16x8 o;
        #pragma unroll
        for (int jj = 0; jj < 8; ++jj) {
            int j = jc * 8 + jj;
            float bv = bf2f(sm[L_BT + swz_idx(j, n >> 3) + (n & 7)]);
            o[jj] = f2bf(bv * __expf(lcLast - lcs[j]));
        }
        *(s16x8*)&sm[L_BW + swz_idx(n, jc)] = o;
    }
    vf4 g[2][4] = {};
    const int rb = (w & 3) * 32, cb = (w >> 2) * 64;
    #pragma unroll
    for (int ks = 0; ks < 4; ++ks) {
        int kc = ks * 4 + lg;
        s16x8 av[2], bv[4];
        #pragma unroll
        for (int i = 0; i < 2; ++i) { int r = rb + i * 16 + lr; av[i] = *(const s16x8*)&sm[L_CT + swz_idx(r, kc)]; }
        #pragma unroll
        for (int jf = 0; jf < 4; ++jf) { int r = cb + jf * 16 + lr; bv[jf] = *(const s16x8*)&sm[L_BT + swz_idx(r, kc)]; }
        #pragma unroll
        for (int i = 0; i < 2; ++i)
            #pragma unroll
            for (int jf = 0; jf < 4; ++jf)
                g[i][jf] = MFMA(av[i], bv[jf], g[i][jf]);
    }
    __syncthreads();

    // P4: write M (masked, decayed, bf16) over BT region
    #pragma unroll
    for (int i = 0; i < 2; ++i)
        #pragma unroll
        for (int jf = 0; jf < 4; ++jf)
            #pragma unroll
            for (int q = 0; q < 4; ++q) {
                int t = rb + i * 16 + lg * 4 + q;
                int j = cb + jf * 16 + lr;
                float v = (j <= t) ? g[i][jf][q] * __expf(lcs[t] - lcs[j]) : 0.f;
                sm[L_BT + swz_idx(t, j >> 3) + (j & 7)] = f2bf(v);
            }
    __syncthreads();

    // P5: Y_intra = M @ XT  and  h_delta = XT @ BW
    vf4 yi[2][2] = {};
    vf4 hdl[4] = {};
    const int prb = (w >> 2) * 32;    // p cols for Y_intra
    const int hrb = (w & 3) * 16;     // p rows for h_delta
    const int hcb = (w >> 2) * 64;    // n cols for h_delta
    #pragma unroll
    for (int ks = 0; ks < 4; ++ks) {
        int kc = ks * 4 + lg;
        s16x8 am[2], bx[2], ax, bw[4];
        #pragma unroll
        for (int i = 0; i < 2; ++i)  { int r = rb + i * 16 + lr;  am[i]  = *(const s16x8*)&sm[L_BT + swz_idx(r, kc)]; }
        #pragma unroll
        for (int jf = 0; jf < 2; ++jf){ int r = prb + jf * 16 + lr; bx[jf] = *(const s16x8*)&sm[L_XT + swz_idx(r, kc)]; }
        { int r = hrb + lr; ax = *(const s16x8*)&sm[L_XT + swz_idx(r, kc)]; }
        #pragma unroll
        for (int jf = 0; jf < 4; ++jf){ int r = hcb + jf * 16 + lr; bw[jf] = *(const s16x8*)&sm[L_BW + swz_idx(r, kc)]; }
        #pragma unroll
        for (int i = 0; i < 2; ++i)
            #pragma unroll
            for (int jf = 0; jf < 2; ++jf)
                yi[i][jf] = MFMA(am[i], bx[jf], yi[i][jf]);
        #pragma unroll
        for (int jf = 0; jf < 4; ++jf)
            hdl[jf] = MFMA(ax, bw[jf], hdl[jf]);
    }

    // epilogue: y = Y_intra + D*x
    float Dh = Dp[h];
    #pragma unroll
    for (int i = 0; i < 2; ++i)
        #pragma unroll
        for (int jf = 0; jf < 2; ++jf)
            #pragma unroll
            for (int q = 0; q < 4; ++q) {
                int t = rb + i * 16 + lg * 4 + q;
                int p = prb + jf * 16 + lr;
                float xv = xrow[(size_t)t * CONV_DIM + h * HEADDIM + p];
                y[(size_t)(bl0 + t) * D_INNER + h * HEADDIM + p] = yi[i][jf][q] + Dh * xv;
            }
    // epilogue: h_delta -> hd16 [k][bh][p][n] bf16
    size_t hb = ((size_t)k * BH + b * NHEADS + h) * (HEADDIM * DSTATE);
    #pragma unroll
    for (int jf = 0; jf < 4; ++jf)
        #pragma unroll
        for (int q = 0; q < 4; ++q) {
            int p = hrb + lg * 4 + q;
            int n = hcb + jf * 16 + lr;
            hd16[hb + p * DSTATE + n] = f2bf(hdl[jf][q]);
        }
}

// ---------------- K3b: sequential chunk-state combine (in place) -----------
// grid = BH = 128 blocks, 512 threads, 16 states each. hd: delta -> h_in.
__global__ __launch_bounds__(512) void ssm_state_b(short* __restrict__ hd16,
                                                   const float* __restrict__ datot) {
    int bh = blockIdx.x;
    int base = threadIdx.x * 16;
    float hs[16];
    #pragma unroll
    for (int i = 0; i < 16; ++i) hs[i] = 0.f;
    #pragma unroll
    for (int k = 0; k < NCHUNK; ++k) {
        size_t off = ((size_t)k * BH + bh) * (HEADDIM * DSTATE) + base;
        float da = datot[k * BH + bh];
        s16x8 d0 = *(const s16x8*)&hd16[off], d1 = *(const s16x8*)&hd16[off + 8];
        s16x8 o0, o1;
        #pragma unroll
        for (int i = 0; i < 8; ++i) { o0[i] = f2bf(hs[i]); o1[i] = f2bf(hs[8 + i]); }
        *(s16x8*)&hd16[off] = o0; *(s16x8*)&hd16[off + 8] = o1;
        #pragma unroll
        for (int i = 0; i < 8; ++i) {
            hs[i]     = fmaf(da, hs[i],     bf2f(d0[i]));
            hs[8 + i] = fmaf(da, hs[8 + i], bf2f(d1[i]));
        }
    }
}

// ---------------- K3c: Y_inter += exp(lc_t) * C @ h_in ----------------
// grid 1024; k==0 exits. LDS: CT only (32KB) -> 4 blocks/CU.
__global__ __launch_bounds__(512) void ssm_mfma_c(const float* __restrict__ xBC,
                                                  const float* __restrict__ dt,
                                                  const float* __restrict__ A_log,
                                                  const short* __restrict__ hd16,
                                                  float* __restrict__ y) {
    int blk = blockIdx.x;
    int h = blk & 31, k = (blk >> 5) & (NCHUNK - 1), b = blk >> 8;
    if (k == 0) return;
    __shared__ short sm[16384];
    __shared__ float dtl[128], lcs[128];
    int tid = threadIdx.x, w = tid >> 6, lane = tid & 63, lr = lane & 15, lg = lane >> 4;
    int bl0 = b * SEQ + k * CHUNK;
    const float* xrow = xBC + (size_t)bl0 * CONV_DIM;

    if (tid < 128) dtl[tid] = dt[(size_t)(bl0 + tid) * NHEADS + h];
    __syncthreads();
    stage_tile(xrow + D_INNER + DSTATE, CONV_DIM, sm, 128, tid);   // C
    float Ah = -__expf(A_log[h]);
    __syncthreads();
    if (w == 0) {
        float a = dtl[lane], bb = dtl[64 + lane];
        #pragma unroll
        for (int d = 1; d < 64; d <<= 1) { float v = __shfl_up(a, d);  if (lane >= d) a  += v; }
        #pragma unroll
        for (int d = 1; d < 64; d <<= 1) { float v = __shfl_up(bb, d); if (lane >= d) bb += v; }
        bb += __shfl(a, 63);
        lcs[lane]      = Ah * a;
        lcs[64 + lane] = Ah * bb;
    }
    __syncthreads();

    const short* hin = hd16 + ((size_t)k * BH + b * NHEADS + h) * (HEADDIM * DSTATE);
    vf4 yi[2][2] = {};
    const int rb = (w & 3) * 32, prb = (w >> 2) * 32;
    #pragma unroll
    for (int ks = 0; ks < 4; ++ks) {
        int kc = ks * 4 + lg;
        s16x8 av[2], bv[2];
        #pragma unroll
        for (int i = 0; i < 2; ++i)  { int r = rb + i * 16 + lr; av[i] = *(const s16x8*)&sm[swz_idx(r, kc)]; }
        #pragma unroll
        for (int jf = 0; jf < 2; ++jf){
            int p = prb + jf * 16 + lr;
            bv[jf] = *(const s16x8*)&hin[p * DSTATE + ks * 32 + lg * 8];
        }
        #pragma unroll
        for (int i = 0; i < 2; ++i)
            #pragma unroll
            for (int jf = 0; jf < 2; ++jf)
                yi[i][jf] = MFMA(av[i], bv[jf], yi[i][jf]);
    }
    #pragma unroll
    for (int i = 0; i < 2; ++i)
        #pragma unroll
        for (int jf = 0; jf < 2; ++jf)
            #pragma unroll
            for (int q = 0; q < 4; ++q) {
                int t = rb + i * 16 + lg * 4 + q;
                int p = prb + jf * 16 + lr;
                float* yp = y + (size_t)(bl0 + t) * D_INNER + h * HEADDIM + p;
                *yp = fmaf(__expf(lcs[t]), yi[i][jf][q], *yp);
            }
}

// ---------------- K4: yz = y*silu(z); RMSNorm(yz)*norm_w -> bf16 ------------
__global__ __launch_bounds__(256) void gate_rmsnorm(const float* __restrict__ y,
                                                    const float* __restrict__ zx,
                                                    const float* __restrict__ nw,
                                                    short* __restrict__ yzb) {
    int bl = blockIdx.x;
    const float* yr = y + (size_t)bl * D_INNER;
    const float* zr = zx + (size_t)bl * D_IN_PROJ;
    int e0 = threadIdx.x * 8;

    float4 y0 = *(const float4*)(yr + e0);
    float4 y1 = *(const float4*)(yr + e0 + 4);
    float4 z0 = *(const float4*)(zr + e0);
    float4 z1 = *(const float4*)(zr + e0 + 4);

    float v[8];
    float zz[8] = {z0.x, z0.y, z0.z, z0.w, z1.x, z1.y, z1.z, z1.w};
    float yy[8] = {y0.x, y0.y, y0.z, y0.w, y1.x, y1.y, y1.z, y1.w};
    float ss = 0.f;
    #pragma unroll
    for (int i = 0; i < 8; ++i) {
        v[i] = yy[i] * zz[i] * sigmoidf_(zz[i]);
        ss = fmaf(v[i], v[i], ss);
    }
    ss += __shfl_xor(ss, 1);  ss += __shfl_xor(ss, 2);  ss += __shfl_xor(ss, 4);
    ss += __shfl_xor(ss, 8);  ss += __shfl_xor(ss, 16); ss += __shfl_xor(ss, 32);
    __shared__ float red[4];
    int wave = threadIdx.x >> 6;
    if ((threadIdx.x & 63) == 0) red[wave] = ss;
    __syncthreads();
    ss = red[0] + red[1] + red[2] + red[3];

    float scale = rsqrtf(ss * (1.f / D_INNER) + EPSF);
    s16x8 o;
    #pragma unroll
    for (int i = 0; i < 8; ++i) o[i] = f2bf(v[i] * scale * nw[e0 + i]);
    *(s16x8*)(yzb + (size_t)bl * D_INNER + e0) = o;
}

// ---------------- launcher ----------------
extern "C" void kernel_launch(void* const* d_in, const int* in_sizes, int n_in,
                              void* d_out, int out_size, void* d_ws, size_t ws_size,
                              hipStream_t stream) {
    const float* x        = (const float*)d_in[0];
    const float* in_w     = (const float*)d_in[1];
    const float* conv_w   = (const float*)d_in[2];
    const float* conv_b   = (const float*)d_in[3];
    const float* dt_bias  = (const float*)d_in[4];
    const float* A_log    = (const float*)d_in[5];
    const float* Dp       = (const float*)d_in[6];
    const float* norm_w   = (const float*)d_in[7];
    const float* out_w    = (const float*)d_in[8];
    float* out            = (float*)d_out;

    float* ws   = (float*)d_ws;
    float* zx   = ws + OFF_ZX;
    float* xBC  = ws + OFF_XBC;
    float* dt   = ws + OFF_DT;
    float* y    = ws + OFF_Y;
    short* sb   = (short*)(ws + FLOAT_END);
    short* xb   = sb + SOFF_XB;
    short* w1b  = sb + SOFF_W1B;
    short* w2b  = sb + SOFF_W2B;
    short* yzb  = sb + SOFF_YZB;
    short* hd16  = xb;                                  // overlay, post-K1
    float* datot = (float*)(hd16 + HD_SHORTS);

    // K0: fp32 -> bf16
    {
        int n = NROWS * DM;
        cvt_bf16<<<n / 4 / 256, 256, 0, stream>>>(x, xb, n, n);
        int ns = D_IN_PROJ * DM, nd = NPAD_IN * DM;
        cvt_bf16<<<nd / 4 / 256, 256, 0, stream>>>(in_w, w1b, ns, nd);
        int n2 = DM * D_INNER;
        cvt_bf16<<<n2 / 4 / 256, 256, 0, stream>>>(out_w, w2b, n2, n2);
    }
    // K1: zxbcdt = x @ in_proj_w^T
    {
        dim3 grid(NPAD_IN / 128, NROWS / 128);
        gemm_mfma<<<grid, 256, 0, stream>>>(xb, w1b, zx, NROWS, DM, D_IN_PROJ);
    }
    // K2: conv + silu
    {
        int total = NROWS * CONV_DIM;
        conv_silu<<<(total + 255) / 256, 256, 0, stream>>>(zx, conv_w, conv_b, xBC);
    }
    // K2b: dt
    {
        int total = NROWS * NHEADS;
        dt_da<<<(total + 255) / 256, 256, 0, stream>>>(zx, dt_bias, dt);
    }
    // K3: chunked MFMA scan
    ssm_mfma_a<<<BATCH * NCHUNK * NHEADS, 512, 0, stream>>>(xBC, dt, A_log, Dp, y, hd16, datot);
    ssm_state_b<<<BH, 512, 0, stream>>>(hd16, datot);
    ssm_mfma_c<<<BATCH * NCHUNK * NHEADS, 512, 0, stream>>>(xBC, dt, A_log, hd16, y);
    // K4: gate + rmsnorm -> bf16
    gate_rmsnorm<<<NROWS, 256, 0, stream>>>(y, zx, norm_w, yzb);
    // K5: out = yz @ out_proj_w^T
    {
        dim3 grid(DM / 128, NROWS / 128);
        gemm_mfma<<<grid, 256, 0, stream>>>(yzb, w2b, out, NROWS, D_INNER, DM);
    }
}

// Round 8
// 337.654 us; speedup vs baseline: 2.3009x; 1.0789x over previous
//
#include <hip/hip_runtime.h>
#include <hip/hip_bf16.h>

#define DM        1024
#define D_INNER   2048
#define NHEADS    32
#define HEADDIM   64
#define DSTATE    128
#define DCONV     4
#define CONV_DIM  (D_INNER + 2*DSTATE)            // 2304
#define D_IN_PROJ (2*D_INNER + 2*DSTATE + NHEADS) // 4384
#define NPAD_IN   4480                            // 35*128, padded N for K1
#define BATCH     4
#define SEQ       1024
#define NROWS     (BATCH*SEQ)                     // 4096
#define EPSF      1e-5f
#define CHUNK     128
#define NCHUNK    (SEQ/CHUNK)                     // 8
#define BH        (BATCH*NHEADS)                  // 128

// ---------------- workspace layout ----------------
#define OFF_ZX   ((size_t)0)                        // [4096][4384]  zxbcdt fp32
#define OFF_XBC  ((size_t)(NROWS)*D_IN_PROJ)        // [4096][2304]
#define OFF_DT   (OFF_XBC + (size_t)NROWS*CONV_DIM) // [4096][32]
#define OFF_DA   (OFF_DT  + (size_t)NROWS*NHEADS)   // [4096][32]
#define OFF_Y    (OFF_DA  + (size_t)NROWS*NHEADS)   // [4096][2048] fp32
#define FLOAT_END (OFF_Y + (size_t)NROWS*D_INNER)
// bf16 (short) region
#define SOFF_XB   ((size_t)0)                           // [4096][1024]  dead after K1
#define SOFF_W1B  (SOFF_XB  + (size_t)NROWS*DM)         // [4480][1024]  dead after K1
#define SOFF_W2B  (SOFF_W1B + (size_t)NPAD_IN*DM)       // [1024][2048]
#define SOFF_YZB  (SOFF_W2B + (size_t)DM*D_INNER)       // [4096][2048]
// h_delta/h_in overlay on xb+w1b: [NCHUNK][BH][64p][128n] bf16 + datot f32
#define HD_SHORTS ((size_t)NCHUNK*BH*HEADDIM*DSTATE)

typedef float  vf4   __attribute__((ext_vector_type(4)));
typedef short  s16x8 __attribute__((ext_vector_type(8)));
typedef short  s16x4 __attribute__((ext_vector_type(4)));
typedef __bf16 bf16x8 __attribute__((ext_vector_type(8)));

__device__ __forceinline__ float sigmoidf_(float x) { return 1.f / (1.f + expf(-x)); }

__device__ __forceinline__ short f2bf(float f) {
    unsigned u = __builtin_bit_cast(unsigned, f);
    u += 0x7fffu + ((u >> 16) & 1u);          // RNE
    return (short)(u >> 16);
}
__device__ __forceinline__ float bf2f(short s) {
    unsigned u = ((unsigned)(unsigned short)s) << 16;
    return __builtin_bit_cast(float, u);
}
__device__ __forceinline__ bf16x8 as_bf(s16x8 v) { return __builtin_bit_cast(bf16x8, v); }
#define MFMA(a,b,c) __builtin_amdgcn_mfma_f32_16x16x32_bf16(as_bf(a), as_bf(b), (c), 0, 0, 0)

__device__ __forceinline__ void gload16(const short* g, short* l) {
    __builtin_amdgcn_global_load_lds(
        (const __attribute__((address_space(1))) unsigned int*)g,
        (__attribute__((address_space(3))) unsigned int*)l, 16, 0, 0);
}

// swizzled [rows][128] bf16 tile: 16B chunk c of row r stored at chunk (c ^ (r&7))
__device__ __forceinline__ int swz_idx(int r, int kc) {
    return r * 128 + (((kc) ^ (r & 7)) << 3);
}
// swizzled [rows][64] bf16 tile (8 chunks/row)
__device__ __forceinline__ int swz64_idx(int r, int c) {
    return r * 64 + (((c) ^ (r & 7)) << 3);
}
// stage [rows][128] f32 global tile -> swizzled bf16 LDS tile (vector, coalesced)
__device__ __forceinline__ void stage_tile(const float* __restrict__ g, int gstride,
                                           short* __restrict__ lds, int rows,
                                           int tid, int nthr) {
    for (int s = tid; s < rows * 16; s += nthr) {
        int r = s >> 4, c = s & 15;
        const float* p = g + (size_t)r * gstride + c * 8;
        float4 v0 = *(const float4*)p, v1 = *(const float4*)(p + 4);
        s16x8 o;
        o[0]=f2bf(v0.x); o[1]=f2bf(v0.y); o[2]=f2bf(v0.z); o[3]=f2bf(v0.w);
        o[4]=f2bf(v1.x); o[5]=f2bf(v1.y); o[6]=f2bf(v1.z); o[7]=f2bf(v1.w);
        *(s16x8*)&lds[swz_idx(r, c)] = o;
    }
}

// ---------------- K0: fp32 -> bf16 convert ----------------
__global__ __launch_bounds__(256) void cvt_bf16(const float* __restrict__ src,
                                                short* __restrict__ dst,
                                                int n_src, int n_dst) {
    int i = (blockIdx.x * 256 + threadIdx.x) * 4;
    if (i >= n_dst) return;
    s16x4 o;
    if (i + 3 < n_src) {
        float4 v = *(const float4*)(src + i);
        o[0] = f2bf(v.x); o[1] = f2bf(v.y); o[2] = f2bf(v.z); o[3] = f2bf(v.w);
    } else {
        #pragma unroll
        for (int j = 0; j < 4; ++j) o[j] = (i + j < n_src) ? f2bf(src[i + j]) : (short)0;
    }
    *(s16x4*)(dst + i) = o;
}

// ---------------- MFMA GEMM (unchanged, proven) ----------------
__global__ __launch_bounds__(256) void gemm_mfma(const short* __restrict__ A,
                                                 const short* __restrict__ B,
                                                 float* __restrict__ C,
                                                 int M, int K, int Nout) {
    __shared__ short smem[16384];
    const int tid = threadIdx.x;
    const int bm = blockIdx.y * 128, bn = blockIdx.x * 128;
    const int lane = tid & 63, lr = lane & 15, lg = lane >> 4;
    const int w = tid >> 6, wm = w >> 1, wn = w & 1;

    const short* ga[4]; const short* gb[4];
    short* la[4]; short* lb[4];
    #pragma unroll
    for (int t = 0; t < 4; ++t) {
        int s = t * 256 + tid;
        int r = s >> 3;
        int c = (s & 7) ^ (r & 7);
        ga[t] = A + (size_t)(bm + r) * K + c * 8;
        gb[t] = B + (size_t)(bn + r) * K + c * 8;
        la[t] = &smem[s * 8];
        lb[t] = &smem[8192 + s * 8];
    }

    vf4 acc[4][4] = {};

    for (int k0 = 0; k0 < K; k0 += 64) {
        __syncthreads();
        #pragma unroll
        for (int t = 0; t < 4; ++t) gload16(ga[t] + k0, la[t]);
        #pragma unroll
        for (int t = 0; t < 4; ++t) gload16(gb[t] + k0, lb[t]);
        __syncthreads();
        #pragma unroll
        for (int kk = 0; kk < 2; ++kk) {
            const int co = ((kk * 4 + lg) ^ (lr & 7)) * 8;
            s16x8 av[4], bv[4];
            #pragma unroll
            for (int f = 0; f < 4; ++f) {
                av[f] = *(const s16x8*)&smem[(wm * 64 + f * 16 + lr) * 64 + co];
                bv[f] = *(const s16x8*)&smem[8192 + (wn * 64 + f * 16 + lr) * 64 + co];
            }
            #pragma unroll
            for (int i = 0; i < 4; ++i)
                #pragma unroll
                for (int j = 0; j < 4; ++j)
                    acc[i][j] = MFMA(av[i], bv[j], acc[i][j]);
        }
    }

    #pragma unroll
    for (int i = 0; i < 4; ++i) {
        int row = bm + wm * 64 + i * 16 + lg * 4;
        #pragma unroll
        for (int j = 0; j < 4; ++j) {
            int col = bn + wn * 64 + j * 16 + lr;
            if (col < Nout) {
                float* cp = C + (size_t)row * Nout + col;
                #pragma unroll
                for (int q = 0; q < 4; ++q) cp[(size_t)q * Nout] = acc[i][j][q];
            }
        }
    }
}

// ---------------- K2: causal depthwise conv(4) + silu ----------------
__global__ __launch_bounds__(256) void conv_silu(const float* __restrict__ zx,
                                                 const float* __restrict__ cw,
                                                 const float* __restrict__ cb,
                                                 float* __restrict__ xBC) {
    int idx = blockIdx.x * 256 + threadIdx.x;
    if (idx >= NROWS * CONV_DIM) return;
    int c  = idx % CONV_DIM;
    int bl = idx / CONV_DIM;
    int b  = bl / SEQ;
    int l  = bl % SEQ;

    float w0 = cw[c*4+0], w1 = cw[c*4+1], w2 = cw[c*4+2], w3 = cw[c*4+3];
    const float* base = zx + (size_t)b * SEQ * D_IN_PROJ + D_INNER + c;

    float acc = cb[c];
    if (l >= 3) acc = fmaf(base[(size_t)(l-3) * D_IN_PROJ], w0, acc);
    if (l >= 2) acc = fmaf(base[(size_t)(l-2) * D_IN_PROJ], w1, acc);
    if (l >= 1) acc = fmaf(base[(size_t)(l-1) * D_IN_PROJ], w2, acc);
    acc = fmaf(base[(size_t)l * D_IN_PROJ], w3, acc);

    xBC[idx] = acc * sigmoidf_(acc);
}

// ---------------- K2b: dt = softplus(dt_raw + bias) ----------------
__global__ __launch_bounds__(256) void dt_da(const float* __restrict__ zx,
                                             const float* __restrict__ dt_bias,
                                             float* __restrict__ dt) {
    int idx = blockIdx.x * 256 + threadIdx.x;
    if (idx >= NROWS * NHEADS) return;
    int h  = idx & (NHEADS - 1);
    int bl = idx >> 5;
    float u = zx[(size_t)bl * D_IN_PROJ + D_INNER + CONV_DIM + h] + dt_bias[h];
    float d = (u > 20.f) ? u : log1pf(expf(u));
    dt[idx] = d;
}

// ---------------- K3a: chunked MFMA scan, intra-chunk ----------------
// grid = B*NCHUNK*NHEADS = 1024, 1024 threads (16 waves).
// LDS regions (shorts): [0,16384) CT then XT; [16384,32768) B then M;
//                       [32768,49152) BW; [49152,57344) XN ([128j][64p]).
#define L_CT 0
#define L_XT 0
#define L_BT 16384
#define L_BW 32768
#define L_XN 49152
__global__ __launch_bounds__(1024) void ssm_mfma_a(const float* __restrict__ xBC,
                                                   const float* __restrict__ dt,
                                                   const float* __restrict__ A_log,
                                                   const float* __restrict__ Dp,
                                                   float* __restrict__ y,
                                                   short* __restrict__ hd16,
                                                   float* __restrict__ datot) {
    __shared__ short sm[57344];
    __shared__ float dtl[128], lcs[128];
    int blk = blockIdx.x;
    int h = blk & 31, k = (blk >> 5) & (NCHUNK - 1), b = blk >> 8;
    int tid = threadIdx.x, w = tid >> 6, lane = tid & 63, lr = lane & 15, lg = lane >> 4;
    int bl0 = b * SEQ + k * CHUNK;
    const float* xrow = xBC + (size_t)bl0 * CONV_DIM;

    // P0: dt slice
    if (tid < 128) dtl[tid] = dt[(size_t)(bl0 + tid) * NHEADS + h];

    // P1: stage C, B (128-wide) and XN=[j][p] (64-wide), all vector+coalesced
    stage_tile(xrow + D_INNER + DSTATE, CONV_DIM, sm + L_CT, 128, tid, 1024);  // C
    stage_tile(xrow + D_INNER,          CONV_DIM, sm + L_BT, 128, tid, 1024);  // B
    {
        int r = tid >> 3, c = tid & 7;            // 1024 slots exactly
        const float* p = xrow + (size_t)r * CONV_DIM + h * HEADDIM + c * 8;
        float4 v0 = *(const float4*)p, v1 = *(const float4*)(p + 4);
        s16x8 o;
        o[0]=f2bf(v0.x); o[1]=f2bf(v0.y); o[2]=f2bf(v0.z); o[3]=f2bf(v0.w);
        o[4]=f2bf(v1.x); o[5]=f2bf(v1.y); o[6]=f2bf(v1.z); o[7]=f2bf(v1.w);
        *(s16x8*)&sm[L_XN + swz64_idx(r, c)] = o;
    }
    __syncthreads();

    // P2 (wave 0): lc = A * inclusive-cumsum(dt) — overlaps other waves' G
    float Ah = -__expf(A_log[h]);
    if (w == 0) {
        float a = dtl[lane], bb = dtl[64 + lane];
        #pragma unroll
        for (int d = 1; d < 64; d <<= 1) { float v = __shfl_up(a, d);  if (lane >= d) a  += v; }
        #pragma unroll
        for (int d = 1; d < 64; d <<= 1) { float v = __shfl_up(bb, d); if (lane >= d) bb += v; }
        bb += __shfl(a, 63);
        lcs[lane]      = Ah * a;
        lcs[64 + lane] = Ah * bb;
        if (lane == 63) datot[k * BH + b * NHEADS + h] = __expf(Ah * bb);
    }

    // G = C @ B^T : 16 waves, each 16 rows x 64 cols
    vf4 g[4] = {};
    const int rb = (w & 7) * 16, cb = (w >> 3) * 64;
    #pragma unroll
    for (int ks = 0; ks < 4; ++ks) {
        int kc = ks * 4 + lg;
        s16x8 av = *(const s16x8*)&sm[L_CT + swz_idx(rb + lr, kc)];
        #pragma unroll
        for (int jf = 0; jf < 4; ++jf) {
            s16x8 bv = *(const s16x8*)&sm[L_BT + swz_idx(cb + jf * 16 + lr, kc)];
            g[jf] = MFMA(av, bv, g[jf]);
        }
    }
    __syncthreads();    // G done reading CT/BT; lcs ready

    float lcLast = lcs[127];

    // P3a: XT[p][j] = dt_j * X[j][p]  (reads XN cols: lanes span p -> 2-way free)
    {
        int p = tid & 63, c2 = tid >> 6;          // c2 = 0..15, exactly covers
        s16x8 o;
        #pragma unroll
        for (int jj = 0; jj < 8; ++jj) {
            int j = c2 * 8 + jj;
            float xv = bf2f(sm[L_XN + swz64_idx(j, p >> 3) + (p & 7)]);
            o[jj] = f2bf(dtl[j] * xv);
        }
        *(s16x8*)&sm[L_XT + swz_idx(p, c2)] = o;
    }
    // P3b: BW[n][j] = B[j][n]*exp(lcLast-lc_j)  (lanes span n -> 2-way free)
    for (int s = tid; s < 2048; s += 1024) {
        int n = s & 127, c = s >> 7;              // c = 0..15 over 2 iters
        s16x8 o;
        #pragma unroll
        for (int jj = 0; jj < 8; ++jj) {
            int j = c * 8 + jj;
            float bv = bf2f(sm[L_BT + swz_idx(j, n >> 3) + (n & 7)]);
            o[jj] = f2bf(bv * __expf(lcLast - lcs[j]));
        }
        *(s16x8*)&sm[L_BW + swz_idx(n, c)] = o;
    }
    __syncthreads();    // BW build done reading BT; XT done reading XN/writing CT

    // P4: write M (masked, decayed) over B region
    #pragma unroll
    for (int jf = 0; jf < 4; ++jf)
        #pragma unroll
        for (int q = 0; q < 4; ++q) {
            int t = rb + lg * 4 + q;
            int j = cb + jf * 16 + lr;
            float v = (j <= t) ? g[jf][q] * __expf(lcs[t] - lcs[j]) : 0.f;
            sm[L_BT + swz_idx(t, j >> 3) + (j & 7)] = f2bf(v);
        }
    __syncthreads();

    // P5: Y_intra = M @ XT  (16 rows x 32 cols / wave)
    //     h_delta = XT @ BW (16 rows x 32 cols / wave)
    vf4 yi[2] = {};
    vf4 hdl[2] = {};
    const int rb2 = (w & 7) * 16, prb = (w >> 3) * 32;
    const int hrb = (w & 3) * 16, hcb = (w >> 2) * 32;
    #pragma unroll
    for (int ks = 0; ks < 4; ++ks) {
        int kc = ks * 4 + lg;
        s16x8 am = *(const s16x8*)&sm[L_BT + swz_idx(rb2 + lr, kc)];
        s16x8 ax = *(const s16x8*)&sm[L_XT + swz_idx(hrb + lr, kc)];
        #pragma unroll
        for (int jf = 0; jf < 2; ++jf) {
            s16x8 bx = *(const s16x8*)&sm[L_XT + swz_idx(prb + jf * 16 + lr, kc)];
            s16x8 bw = *(const s16x8*)&sm[L_BW + swz_idx(hcb + jf * 16 + lr, kc)];
            yi[jf]  = MFMA(am, bx, yi[jf]);
            hdl[jf] = MFMA(ax, bw, hdl[jf]);
        }
    }

    // epilogue: y = Y_intra + D*x
    float Dh = Dp[h];
    #pragma unroll
    for (int jf = 0; jf < 2; ++jf)
        #pragma unroll
        for (int q = 0; q < 4; ++q) {
            int t = rb2 + lg * 4 + q;
            int p = prb + jf * 16 + lr;
            float xv = xrow[(size_t)t * CONV_DIM + h * HEADDIM + p];
            y[(size_t)(bl0 + t) * D_INNER + h * HEADDIM + p] = yi[jf][q] + Dh * xv;
        }
    // epilogue: h_delta -> hd16 [k][bh][p][n] bf16
    size_t hb = ((size_t)k * BH + b * NHEADS + h) * (HEADDIM * DSTATE);
    #pragma unroll
    for (int jf = 0; jf < 2; ++jf)
        #pragma unroll
        for (int q = 0; q < 4; ++q) {
            int p = hrb + lg * 4 + q;
            int n = hcb + jf * 16 + lr;
            hd16[hb + p * DSTATE + n] = f2bf(hdl[jf][q]);
        }
}

// ---------------- K3b: sequential chunk-state combine (in place) -----------
__global__ __launch_bounds__(512) void ssm_state_b(short* __restrict__ hd16,
                                                   const float* __restrict__ datot) {
    int bh = blockIdx.x;
    int base = threadIdx.x * 16;
    float hs[16];
    #pragma unroll
    for (int i = 0; i < 16; ++i) hs[i] = 0.f;
    #pragma unroll
    for (int k = 0; k < NCHUNK; ++k) {
        size_t off = ((size_t)k * BH + bh) * (HEADDIM * DSTATE) + base;
        float da = datot[k * BH + bh];
        s16x8 d0 = *(const s16x8*)&hd16[off], d1 = *(const s16x8*)&hd16[off + 8];
        s16x8 o0, o1;
        #pragma unroll
        for (int i = 0; i < 8; ++i) { o0[i] = f2bf(hs[i]); o1[i] = f2bf(hs[8 + i]); }
        *(s16x8*)&hd16[off] = o0; *(s16x8*)&hd16[off + 8] = o1;
        #pragma unroll
        for (int i = 0; i < 8; ++i) {
            hs[i]     = fmaf(da, hs[i],     bf2f(d0[i]));
            hs[8 + i] = fmaf(da, hs[8 + i], bf2f(d1[i]));
        }
    }
}

// ---------------- K3c: Y_inter += exp(lc_t) * C @ h_in ----------------
__global__ __launch_bounds__(512) void ssm_mfma_c(const float* __restrict__ xBC,
                                                  const float* __restrict__ dt,
                                                  const float* __restrict__ A_log,
                                                  const short* __restrict__ hd16,
                                                  float* __restrict__ y) {
    int blk = blockIdx.x;
    int h = blk & 31, k = (blk >> 5) & (NCHUNK - 1), b = blk >> 8;
    if (k == 0) return;
    __shared__ short sm[16384];
    __shared__ float dtl[128], lcs[128];
    int tid = threadIdx.x, w = tid >> 6, lane = tid & 63, lr = lane & 15, lg = lane >> 4;
    int bl0 = b * SEQ + k * CHUNK;
    const float* xrow = xBC + (size_t)bl0 * CONV_DIM;

    if (tid < 128) dtl[tid] = dt[(size_t)(bl0 + tid) * NHEADS + h];
    __syncthreads();
    stage_tile(xrow + D_INNER + DSTATE, CONV_DIM, sm, 128, tid, 512);   // C
    float Ah = -__expf(A_log[h]);
    __syncthreads();
    if (w == 0) {
        float a = dtl[lane], bb = dtl[64 + lane];
        #pragma unroll
        for (int d = 1; d < 64; d <<= 1) { float v = __shfl_up(a, d);  if (lane >= d) a  += v; }
        #pragma unroll
        for (int d = 1; d < 64; d <<= 1) { float v = __shfl_up(bb, d); if (lane >= d) bb += v; }
        bb += __shfl(a, 63);
        lcs[lane]      = Ah * a;
        lcs[64 + lane] = Ah * bb;
    }
    __syncthreads();

    const short* hin = hd16 + ((size_t)k * BH + b * NHEADS + h) * (HEADDIM * DSTATE);
    vf4 yi[2][2] = {};
    const int rb = (w & 3) * 32, prb = (w >> 2) * 32;
    #pragma unroll
    for (int ks = 0; ks < 4; ++ks) {
        int kc = ks * 4 + lg;
        s16x8 av[2], bv[2];
        #pragma unroll
        for (int i = 0; i < 2; ++i)  { int r = rb + i * 16 + lr; av[i] = *(const s16x8*)&sm[swz_idx(r, kc)]; }
        #pragma unroll
        for (int jf = 0; jf < 2; ++jf){
            int p = prb + jf * 16 + lr;
            bv[jf] = *(const s16x8*)&hin[p * DSTATE + ks * 32 + lg * 8];
        }
        #pragma unroll
        for (int i = 0; i < 2; ++i)
            #pragma unroll
            for (int jf = 0; jf < 2; ++jf)
                yi[i][jf] = MFMA(av[i], bv[jf], yi[i][jf]);
    }
    #pragma unroll
    for (int i = 0; i < 2; ++i)
        #pragma unroll
        for (int jf = 0; jf < 2; ++jf)
            #pragma unroll
            for (int q = 0; q < 4; ++q) {
                int t = rb + i * 16 + lg * 4 + q;
                int p = prb + jf * 16 + lr;
                float* yp = y + (size_t)(bl0 + t) * D_INNER + h * HEADDIM + p;
                *yp = fmaf(__expf(lcs[t]), yi[i][jf][q], *yp);
            }
}

// ---------------- K4: yz = y*silu(z); RMSNorm(yz)*norm_w -> bf16 ------------
__global__ __launch_bounds__(256) void gate_rmsnorm(const float* __restrict__ y,
                                                    const float* __restrict__ zx,
                                                    const float* __restrict__ nw,
                                                    short* __restrict__ yzb) {
    int bl = blockIdx.x;
    const float* yr = y + (size_t)bl * D_INNER;
    const float* zr = zx + (size_t)bl * D_IN_PROJ;
    int e0 = threadIdx.x * 8;

    float4 y0 = *(const float4*)(yr + e0);
    float4 y1 = *(const float4*)(yr + e0 + 4);
    float4 z0 = *(const float4*)(zr + e0);
    float4 z1 = *(const float4*)(zr + e0 + 4);

    float v[8];
    float zz[8] = {z0.x, z0.y, z0.z, z0.w, z1.x, z1.y, z1.z, z1.w};
    float yy[8] = {y0.x, y0.y, y0.z, y0.w, y1.x, y1.y, y1.z, y1.w};
    float ss = 0.f;
    #pragma unroll
    for (int i = 0; i < 8; ++i) {
        v[i] = yy[i] * zz[i] * sigmoidf_(zz[i]);
        ss = fmaf(v[i], v[i], ss);
    }
    ss += __shfl_xor(ss, 1);  ss += __shfl_xor(ss, 2);  ss += __shfl_xor(ss, 4);
    ss += __shfl_xor(ss, 8);  ss += __shfl_xor(ss, 16); ss += __shfl_xor(ss, 32);
    __shared__ float red[4];
    int wave = threadIdx.x >> 6;
    if ((threadIdx.x & 63) == 0) red[wave] = ss;
    __syncthreads();
    ss = red[0] + red[1] + red[2] + red[3];

    float scale = rsqrtf(ss * (1.f / D_INNER) + EPSF);
    s16x8 o;
    #pragma unroll
    for (int i = 0; i < 8; ++i) o[i] = f2bf(v[i] * scale * nw[e0 + i]);
    *(s16x8*)(yzb + (size_t)bl * D_INNER + e0) = o;
}

// ---------------- launcher ----------------
extern "C" void kernel_launch(void* const* d_in, const int* in_sizes, int n_in,
                              void* d_out, int out_size, void* d_ws, size_t ws_size,
                              hipStream_t stream) {
    const float* x        = (const float*)d_in[0];
    const float* in_w     = (const float*)d_in[1];
    const float* conv_w   = (const float*)d_in[2];
    const float* conv_b   = (const float*)d_in[3];
    const float* dt_bias  = (const float*)d_in[4];
    const float* A_log    = (const float*)d_in[5];
    const float* Dp       = (const float*)d_in[6];
    const float* norm_w   = (const float*)d_in[7];
    const float* out_w    = (const float*)d_in[8];
    float* out            = (float*)d_out;

    float* ws   = (float*)d_ws;
    float* zx   = ws + OFF_ZX;
    float* xBC  = ws + OFF_XBC;
    float* dt   = ws + OFF_DT;
    float* y    = ws + OFF_Y;
    short* sb   = (short*)(ws + FLOAT_END);
    short* xb   = sb + SOFF_XB;
    short* w1b  = sb + SOFF_W1B;
    short* w2b  = sb + SOFF_W2B;
    short* yzb  = sb + SOFF_YZB;
    short* hd16  = xb;                                  // overlay, post-K1
    float* datot = (float*)(hd16 + HD_SHORTS);

    // K0: fp32 -> bf16
    {
        int n = NROWS * DM;
        cvt_bf16<<<n / 4 / 256, 256, 0, stream>>>(x, xb, n, n);
        int ns = D_IN_PROJ * DM, nd = NPAD_IN * DM;
        cvt_bf16<<<nd / 4 / 256, 256, 0, stream>>>(in_w, w1b, ns, nd);
        int n2 = DM * D_INNER;
        cvt_bf16<<<n2 / 4 / 256, 256, 0, stream>>>(out_w, w2b, n2, n2);
    }
    // K1: zxbcdt = x @ in_proj_w^T
    {
        dim3 grid(NPAD_IN / 128, NROWS / 128);
        gemm_mfma<<<grid, 256, 0, stream>>>(xb, w1b, zx, NROWS, DM, D_IN_PROJ);
    }
    // K2: conv + silu
    {
        int total = NROWS * CONV_DIM;
        conv_silu<<<(total + 255) / 256, 256, 0, stream>>>(zx, conv_w, conv_b, xBC);
    }
    // K2b: dt
    {
        int total = NROWS * NHEADS;
        dt_da<<<(total + 255) / 256, 256, 0, stream>>>(zx, dt_bias, dt);
    }
    // K3: chunked MFMA scan
    ssm_mfma_a<<<BATCH * NCHUNK * NHEADS, 1024, 0, stream>>>(xBC, dt, A_log, Dp, y, hd16, datot);
    ssm_state_b<<<BH, 512, 0, stream>>>(hd16, datot);
    ssm_mfma_c<<<BATCH * NCHUNK * NHEADS, 512, 0, stream>>>(xBC, dt, A_log, hd16, y);
    // K4: gate + rmsnorm -> bf16
    gate_rmsnorm<<<NROWS, 256, 0, stream>>>(y, zx, norm_w, yzb);
    // K5: out = yz @ out_proj_w^T
    {
        dim3 grid(DM / 128, NROWS / 128);
        gemm_mfma<<<grid, 256, 0, stream>>>(yzb, w2b, out, NROWS, D_INNER, DM);
    }
}

// Round 9
// 309.100 us; speedup vs baseline: 2.5134x; 1.0924x over previous
//
#include <hip/hip_runtime.h>
#include <hip/hip_bf16.h>

#define DM        1024
#define D_INNER   2048
#define NHEADS    32
#define HEADDIM   64
#define DSTATE    128
#define DCONV     4
#define CONV_DIM  (D_INNER + 2*DSTATE)            // 2304
#define D_IN_PROJ (2*D_INNER + 2*DSTATE + NHEADS) // 4384
#define NPAD_IN   4480                            // 35*128, padded N for K1
#define BATCH     4
#define SEQ       1024
#define NROWS     (BATCH*SEQ)                     // 4096
#define EPSF      1e-5f
#define CHUNK     128
#define NCHUNK    (SEQ/CHUNK)                     // 8
#define BH        (BATCH*NHEADS)                  // 128

// ---------------- workspace layout ----------------
// zx is now bf16 (shorts), occupying the old fp32 slot (half used)
#define OFF_ZX   ((size_t)0)                        // [4096][4384] bf16 zxbcdt
#define OFF_XBC  ((size_t)(NROWS)*D_IN_PROJ)        // [4096][2304] fp32
#define OFF_DT   (OFF_XBC + (size_t)NROWS*CONV_DIM) // [4096][32]
#define OFF_DA   (OFF_DT  + (size_t)NROWS*NHEADS)   // [4096][32]
#define OFF_Y    (OFF_DA  + (size_t)NROWS*NHEADS)   // [4096][2048] fp32
#define FLOAT_END (OFF_Y + (size_t)NROWS*D_INNER)
// bf16 (short) region
#define SOFF_XB   ((size_t)0)                           // [4096][1024]  dead after K1
#define SOFF_W1B  (SOFF_XB  + (size_t)NROWS*DM)         // [4480][1024]  dead after K1
#define SOFF_W2B  (SOFF_W1B + (size_t)NPAD_IN*DM)       // [1024][2048]
#define SOFF_YZB  (SOFF_W2B + (size_t)DM*D_INNER)       // [4096][2048]
#define HD_SHORTS ((size_t)NCHUNK*BH*HEADDIM*DSTATE)

typedef float  vf4   __attribute__((ext_vector_type(4)));
typedef short  s16x8 __attribute__((ext_vector_type(8)));
typedef short  s16x4 __attribute__((ext_vector_type(4)));
typedef __bf16 bf16x8 __attribute__((ext_vector_type(8)));

__device__ __forceinline__ float sigmoidf_(float x) { return 1.f / (1.f + expf(-x)); }

__device__ __forceinline__ short f2bf(float f) {
    unsigned u = __builtin_bit_cast(unsigned, f);
    u += 0x7fffu + ((u >> 16) & 1u);          // RNE
    return (short)(u >> 16);
}
__device__ __forceinline__ float bf2f(short s) {
    unsigned u = ((unsigned)(unsigned short)s) << 16;
    return __builtin_bit_cast(float, u);
}
__device__ __forceinline__ bf16x8 as_bf(s16x8 v) { return __builtin_bit_cast(bf16x8, v); }
#define MFMA(a,b,c) __builtin_amdgcn_mfma_f32_16x16x32_bf16(as_bf(a), as_bf(b), (c), 0, 0, 0)

template <typename T> __device__ __forceinline__ T cvt_out(float v);
template <> __device__ __forceinline__ float cvt_out<float>(float v) { return v; }
template <> __device__ __forceinline__ short cvt_out<short>(float v) { return f2bf(v); }

__device__ __forceinline__ void gload16(const short* g, short* l) {
    __builtin_amdgcn_global_load_lds(
        (const __attribute__((address_space(1))) unsigned int*)g,
        (__attribute__((address_space(3))) unsigned int*)l, 16, 0, 0);
}

// swizzled [rows][128] bf16 tile: 16B chunk c of row r stored at chunk (c ^ (r&7))
__device__ __forceinline__ int swz_idx(int r, int kc) {
    return r * 128 + (((kc) ^ (r & 7)) << 3);
}
// swizzled [rows][64] bf16 tile
__device__ __forceinline__ int swz64_idx(int r, int c) {
    return r * 64 + (((c) ^ (r & 7)) << 3);
}
// stage [rows][128] f32 global tile -> swizzled bf16 LDS tile (vector, coalesced)
__device__ __forceinline__ void stage_tile(const float* __restrict__ g, int gstride,
                                           short* __restrict__ lds, int rows,
                                           int tid, int nthr) {
    for (int s = tid; s < rows * 16; s += nthr) {
        int r = s >> 4, c = s & 15;
        const float* p = g + (size_t)r * gstride + c * 8;
        float4 v0 = *(const float4*)p, v1 = *(const float4*)(p + 4);
        s16x8 o;
        o[0]=f2bf(v0.x); o[1]=f2bf(v0.y); o[2]=f2bf(v0.z); o[3]=f2bf(v0.w);
        o[4]=f2bf(v1.x); o[5]=f2bf(v1.y); o[6]=f2bf(v1.z); o[7]=f2bf(v1.w);
        *(s16x8*)&lds[swz_idx(r, c)] = o;
    }
}

// ---------------- K0: fp32 -> bf16 convert ----------------
__global__ __launch_bounds__(256) void cvt_bf16(const float* __restrict__ src,
                                                short* __restrict__ dst,
                                                int n_src, int n_dst) {
    int i = (blockIdx.x * 256 + threadIdx.x) * 4;
    if (i >= n_dst) return;
    s16x4 o;
    if (i + 3 < n_src) {
        float4 v = *(const float4*)(src + i);
        o[0] = f2bf(v.x); o[1] = f2bf(v.y); o[2] = f2bf(v.z); o[3] = f2bf(v.w);
    } else {
        #pragma unroll
        for (int j = 0; j < 4; ++j) o[j] = (i + j < n_src) ? f2bf(src[i + j]) : (short)0;
    }
    *(s16x4*)(dst + i) = o;
}

// ---------------- MFMA GEMM, flat grid + XCD-bijective swizzle --------------
// grid.x must be % 8. C[M][Nout] = A[M][K] * B[Npad][K]^T, OutT in {float,short}.
template <typename OutT>
__global__ __launch_bounds__(256) void gemm_mfma(const short* __restrict__ A,
                                                 const short* __restrict__ B,
                                                 OutT* __restrict__ C,
                                                 int K, int Nout, int nbx) {
    __shared__ short smem[16384];
    const int tid = threadIdx.x;
    // XCD swizzle: 8 XCDs, contiguous chunk per XCD (bijective: gridDim.x%8==0)
    const int cpx = gridDim.x >> 3;
    const int wgid = (blockIdx.x & 7) * cpx + (blockIdx.x >> 3);
    const int bm = (wgid / nbx) * 128, bn = (wgid % nbx) * 128;
    const int lane = tid & 63, lr = lane & 15, lg = lane >> 4;
    const int w = tid >> 6, wm = w >> 1, wn = w & 1;

    const short* ga[4]; const short* gb[4];
    short* la[4]; short* lb[4];
    #pragma unroll
    for (int t = 0; t < 4; ++t) {
        int s = t * 256 + tid;
        int r = s >> 3;
        int c = (s & 7) ^ (r & 7);
        ga[t] = A + (size_t)(bm + r) * K + c * 8;
        gb[t] = B + (size_t)(bn + r) * K + c * 8;
        la[t] = &smem[s * 8];
        lb[t] = &smem[8192 + s * 8];
    }

    vf4 acc[4][4] = {};

    for (int k0 = 0; k0 < K; k0 += 64) {
        __syncthreads();
        #pragma unroll
        for (int t = 0; t < 4; ++t) gload16(ga[t] + k0, la[t]);
        #pragma unroll
        for (int t = 0; t < 4; ++t) gload16(gb[t] + k0, lb[t]);
        __syncthreads();
        #pragma unroll
        for (int kk = 0; kk < 2; ++kk) {
            const int co = ((kk * 4 + lg) ^ (lr & 7)) * 8;
            s16x8 av[4], bv[4];
            #pragma unroll
            for (int f = 0; f < 4; ++f) {
                av[f] = *(const s16x8*)&smem[(wm * 64 + f * 16 + lr) * 64 + co];
                bv[f] = *(const s16x8*)&smem[8192 + (wn * 64 + f * 16 + lr) * 64 + co];
            }
            #pragma unroll
            for (int i = 0; i < 4; ++i)
                #pragma unroll
                for (int j = 0; j < 4; ++j)
                    acc[i][j] = MFMA(av[i], bv[j], acc[i][j]);
        }
    }

    #pragma unroll
    for (int i = 0; i < 4; ++i) {
        int row = bm + wm * 64 + i * 16 + lg * 4;
        #pragma unroll
        for (int j = 0; j < 4; ++j) {
            int col = bn + wn * 64 + j * 16 + lr;
            if (col < Nout) {
                OutT* cp = C + (size_t)row * Nout + col;
                #pragma unroll
                for (int q = 0; q < 4; ++q) cp[(size_t)q * Nout] = cvt_out<OutT>(acc[i][j][q]);
            }
        }
    }
}

// ---------------- K2: causal depthwise conv(4) + silu (bf16 in, f32 out) ----
__global__ __launch_bounds__(256) void conv_silu(const short* __restrict__ zx,
                                                 const float* __restrict__ cw,
                                                 const float* __restrict__ cb,
                                                 float* __restrict__ xBC) {
    int idx = blockIdx.x * 256 + threadIdx.x;
    if (idx >= NROWS * CONV_DIM) return;
    int c  = idx % CONV_DIM;
    int bl = idx / CONV_DIM;
    int b  = bl / SEQ;
    int l  = bl % SEQ;

    float w0 = cw[c*4+0], w1 = cw[c*4+1], w2 = cw[c*4+2], w3 = cw[c*4+3];
    const short* base = zx + (size_t)b * SEQ * D_IN_PROJ + D_INNER + c;

    float acc = cb[c];
    if (l >= 3) acc = fmaf(bf2f(base[(size_t)(l-3) * D_IN_PROJ]), w0, acc);
    if (l >= 2) acc = fmaf(bf2f(base[(size_t)(l-2) * D_IN_PROJ]), w1, acc);
    if (l >= 1) acc = fmaf(bf2f(base[(size_t)(l-1) * D_IN_PROJ]), w2, acc);
    acc = fmaf(bf2f(base[(size_t)l * D_IN_PROJ]), w3, acc);

    xBC[idx] = acc * sigmoidf_(acc);
}

// ---------------- K2b: dt = softplus(dt_raw + bias) ----------------
__global__ __launch_bounds__(256) void dt_da(const short* __restrict__ zx,
                                             const float* __restrict__ dt_bias,
                                             float* __restrict__ dt) {
    int idx = blockIdx.x * 256 + threadIdx.x;
    if (idx >= NROWS * NHEADS) return;
    int h  = idx & (NHEADS - 1);
    int bl = idx >> 5;
    float u = bf2f(zx[(size_t)bl * D_IN_PROJ + D_INNER + CONV_DIM + h]) + dt_bias[h];
    float d = (u > 20.f) ? u : log1pf(expf(u));
    dt[idx] = d;
}

// ---------------- K3a: chunked MFMA scan, intra-chunk ----------------
#define L_CT 0
#define L_XT 0
#define L_BT 16384
#define L_BW 32768
#define L_XN 49152
__global__ __launch_bounds__(1024) void ssm_mfma_a(const float* __restrict__ xBC,
                                                   const float* __restrict__ dt,
                                                   const float* __restrict__ A_log,
                                                   const float* __restrict__ Dp,
                                                   float* __restrict__ y,
                                                   short* __restrict__ hd16,
                                                   float* __restrict__ datot) {
    __shared__ short sm[57344];
    __shared__ float dtl[128], lcs[128];
    // XCD swizzle: blocks sharing (b,k) (same B/C tiles) land on one XCD's L2
    int blk = (blockIdx.x & 7) * (gridDim.x >> 3) + (blockIdx.x >> 3);
    int h = blk & 31, k = (blk >> 5) & (NCHUNK - 1), b = blk >> 8;
    int tid = threadIdx.x, w = tid >> 6, lane = tid & 63, lr = lane & 15, lg = lane >> 4;
    int bl0 = b * SEQ + k * CHUNK;
    const float* xrow = xBC + (size_t)bl0 * CONV_DIM;

    // P0: dt slice
    if (tid < 128) dtl[tid] = dt[(size_t)(bl0 + tid) * NHEADS + h];

    // P1: stage C, B (128-wide) and XN=[j][p] (64-wide), all vector+coalesced
    stage_tile(xrow + D_INNER + DSTATE, CONV_DIM, sm + L_CT, 128, tid, 1024);  // C
    stage_tile(xrow + D_INNER,          CONV_DIM, sm + L_BT, 128, tid, 1024);  // B
    {
        int r = tid >> 3, c = tid & 7;            // 1024 slots exactly
        const float* p = xrow + (size_t)r * CONV_DIM + h * HEADDIM + c * 8;
        float4 v0 = *(const float4*)p, v1 = *(const float4*)(p + 4);
        s16x8 o;
        o[0]=f2bf(v0.x); o[1]=f2bf(v0.y); o[2]=f2bf(v0.z); o[3]=f2bf(v0.w);
        o[4]=f2bf(v1.x); o[5]=f2bf(v1.y); o[6]=f2bf(v1.z); o[7]=f2bf(v1.w);
        *(s16x8*)&sm[L_XN + swz64_idx(r, c)] = o;
    }
    __syncthreads();

    // P2 (wave 0): lc = A * inclusive-cumsum(dt) — overlaps other waves' G
    float Ah = -__expf(A_log[h]);
    if (w == 0) {
        float a = dtl[lane], bb = dtl[64 + lane];
        #pragma unroll
        for (int d = 1; d < 64; d <<= 1) { float v = __shfl_up(a, d);  if (lane >= d) a  += v; }
        #pragma unroll
        for (int d = 1; d < 64; d <<= 1) { float v = __shfl_up(bb, d); if (lane >= d) bb += v; }
        bb += __shfl(a, 63);
        lcs[lane]      = Ah * a;
        lcs[64 + lane] = Ah * bb;
        if (lane == 63) datot[k * BH + b * NHEADS + h] = __expf(Ah * bb);
    }

    // G = C @ B^T : 16 waves, each 16 rows x 64 cols
    vf4 g[4] = {};
    const int rb = (w & 7) * 16, cb = (w >> 3) * 64;
    #pragma unroll
    for (int ks = 0; ks < 4; ++ks) {
        int kc = ks * 4 + lg;
        s16x8 av = *(const s16x8*)&sm[L_CT + swz_idx(rb + lr, kc)];
        #pragma unroll
        for (int jf = 0; jf < 4; ++jf) {
            s16x8 bv = *(const s16x8*)&sm[L_BT + swz_idx(cb + jf * 16 + lr, kc)];
            g[jf] = MFMA(av, bv, g[jf]);
        }
    }
    __syncthreads();    // G done reading CT/BT; lcs ready

    float lcLast = lcs[127];

    // P3a: XT[p][j] = dt_j * X[j][p]  (reads XN cols: lanes span p -> 2-way free)
    {
        int p = tid & 63, c2 = tid >> 6;
        s16x8 o;
        #pragma unroll
        for (int jj = 0; jj < 8; ++jj) {
            int j = c2 * 8 + jj;
            float xv = bf2f(sm[L_XN + swz64_idx(j, p >> 3) + (p & 7)]);
            o[jj] = f2bf(dtl[j] * xv);
        }
        *(s16x8*)&sm[L_XT + swz_idx(p, c2)] = o;
    }
    // P3b: BW[n][j] = B[j][n]*exp(lcLast-lc_j)  (lanes span n -> 2-way free)
    for (int s = tid; s < 2048; s += 1024) {
        int n = s & 127, c = s >> 7;
        s16x8 o;
        #pragma unroll
        for (int jj = 0; jj < 8; ++jj) {
            int j = c * 8 + jj;
            float bv = bf2f(sm[L_BT + swz_idx(j, n >> 3) + (n & 7)]);
            o[jj] = f2bf(bv * __expf(lcLast - lcs[j]));
        }
        *(s16x8*)&sm[L_BW + swz_idx(n, c)] = o;
    }
    __syncthreads();

    // P4: write M (masked, decayed) over B region
    #pragma unroll
    for (int jf = 0; jf < 4; ++jf)
        #pragma unroll
        for (int q = 0; q < 4; ++q) {
            int t = rb + lg * 4 + q;
            int j = cb + jf * 16 + lr;
            float v = (j <= t) ? g[jf][q] * __expf(lcs[t] - lcs[j]) : 0.f;
            sm[L_BT + swz_idx(t, j >> 3) + (j & 7)] = f2bf(v);
        }
    __syncthreads();

    // P5: Y_intra = M @ XT ; h_delta = XT @ BW
    vf4 yi[2] = {};
    vf4 hdl[2] = {};
    const int rb2 = (w & 7) * 16, prb = (w >> 3) * 32;
    const int hrb = (w & 3) * 16, hcb = (w >> 2) * 32;
    #pragma unroll
    for (int ks = 0; ks < 4; ++ks) {
        int kc = ks * 4 + lg;
        s16x8 am = *(const s16x8*)&sm[L_BT + swz_idx(rb2 + lr, kc)];
        s16x8 ax = *(const s16x8*)&sm[L_XT + swz_idx(hrb + lr, kc)];
        #pragma unroll
        for (int jf = 0; jf < 2; ++jf) {
            s16x8 bx = *(const s16x8*)&sm[L_XT + swz_idx(prb + jf * 16 + lr, kc)];
            s16x8 bw = *(const s16x8*)&sm[L_BW + swz_idx(hcb + jf * 16 + lr, kc)];
            yi[jf]  = MFMA(am, bx, yi[jf]);
            hdl[jf] = MFMA(ax, bw, hdl[jf]);
        }
    }

    // epilogue: y = Y_intra + D*x
    float Dh = Dp[h];
    #pragma unroll
    for (int jf = 0; jf < 2; ++jf)
        #pragma unroll
        for (int q = 0; q < 4; ++q) {
            int t = rb2 + lg * 4 + q;
            int p = prb + jf * 16 + lr;
            float xv = xrow[(size_t)t * CONV_DIM + h * HEADDIM + p];
            y[(size_t)(bl0 + t) * D_INNER + h * HEADDIM + p] = yi[jf][q] + Dh * xv;
        }
    // epilogue: h_delta -> hd16 [k][bh][p][n] bf16
    size_t hb = ((size_t)k * BH + b * NHEADS + h) * (HEADDIM * DSTATE);
    #pragma unroll
    for (int jf = 0; jf < 2; ++jf)
        #pragma unroll
        for (int q = 0; q < 4; ++q) {
            int p = hrb + lg * 4 + q;
            int n = hcb + jf * 16 + lr;
            hd16[hb + p * DSTATE + n] = f2bf(hdl[jf][q]);
        }
}

// ---------------- K3b: sequential chunk-state combine (in place) -----------
__global__ __launch_bounds__(512) void ssm_state_b(short* __restrict__ hd16,
                                                   const float* __restrict__ datot) {
    int bh = blockIdx.x;
    int base = threadIdx.x * 16;
    float hs[16];
    #pragma unroll
    for (int i = 0; i < 16; ++i) hs[i] = 0.f;
    #pragma unroll
    for (int k = 0; k < NCHUNK; ++k) {
        size_t off = ((size_t)k * BH + bh) * (HEADDIM * DSTATE) + base;
        float da = datot[k * BH + bh];
        s16x8 d0 = *(const s16x8*)&hd16[off], d1 = *(const s16x8*)&hd16[off + 8];
        s16x8 o0, o1;
        #pragma unroll
        for (int i = 0; i < 8; ++i) { o0[i] = f2bf(hs[i]); o1[i] = f2bf(hs[8 + i]); }
        *(s16x8*)&hd16[off] = o0; *(s16x8*)&hd16[off + 8] = o1;
        #pragma unroll
        for (int i = 0; i < 8; ++i) {
            hs[i]     = fmaf(da, hs[i],     bf2f(d0[i]));
            hs[8 + i] = fmaf(da, hs[8 + i], bf2f(d1[i]));
        }
    }
}

// ---------------- K3c: Y_inter += exp(lc_t) * C @ h_in ----------------
__global__ __launch_bounds__(512) void ssm_mfma_c(const float* __restrict__ xBC,
                                                  const float* __restrict__ dt,
                                                  const float* __restrict__ A_log,
                                                  const short* __restrict__ hd16,
                                                  float* __restrict__ y) {
    int blk = (blockIdx.x & 7) * (gridDim.x >> 3) + (blockIdx.x >> 3);
    int h = blk & 31, k = (blk >> 5) & (NCHUNK - 1), b = blk >> 8;
    if (k == 0) return;
    __shared__ short sm[16384];
    __shared__ float dtl[128], lcs[128];
    int tid = threadIdx.x, w = tid >> 6, lane = tid & 63, lr = lane & 15, lg = lane >> 4;
    int bl0 = b * SEQ + k * CHUNK;
    const float* xrow = xBC + (size_t)bl0 * CONV_DIM;

    if (tid < 128) dtl[tid] = dt[(size_t)(bl0 + tid) * NHEADS + h];
    __syncthreads();
    stage_tile(xrow + D_INNER + DSTATE, CONV_DIM, sm, 128, tid, 512);   // C
    float Ah = -__expf(A_log[h]);
    __syncthreads();
    if (w == 0) {
        float a = dtl[lane], bb = dtl[64 + lane];
        #pragma unroll
        for (int d = 1; d < 64; d <<= 1) { float v = __shfl_up(a, d);  if (lane >= d) a  += v; }
        #pragma unroll
        for (int d = 1; d < 64; d <<= 1) { float v = __shfl_up(bb, d); if (lane >= d) bb += v; }
        bb += __shfl(a, 63);
        lcs[lane]      = Ah * a;
        lcs[64 + lane] = Ah * bb;
    }
    __syncthreads();

    const short* hin = hd16 + ((size_t)k * BH + b * NHEADS + h) * (HEADDIM * DSTATE);
    vf4 yi[2][2] = {};
    const int rb = (w & 3) * 32, prb = (w >> 2) * 32;
    #pragma unroll
    for (int ks = 0; ks < 4; ++ks) {
        int kc = ks * 4 + lg;
        s16x8 av[2], bv[2];
        #pragma unroll
        for (int i = 0; i < 2; ++i)  { int r = rb + i * 16 + lr; av[i] = *(const s16x8*)&sm[swz_idx(r, kc)]; }
        #pragma unroll
        for (int jf = 0; jf < 2; ++jf){
            int p = prb + jf * 16 + lr;
            bv[jf] = *(const s16x8*)&hin[p * DSTATE + ks * 32 + lg * 8];
        }
        #pragma unroll
        for (int i = 0; i < 2; ++i)
            #pragma unroll
            for (int jf = 0; jf < 2; ++jf)
                yi[i][jf] = MFMA(av[i], bv[jf], yi[i][jf]);
    }
    #pragma unroll
    for (int i = 0; i < 2; ++i)
        #pragma unroll
        for (int jf = 0; jf < 2; ++jf)
            #pragma unroll
            for (int q = 0; q < 4; ++q) {
                int t = rb + i * 16 + lg * 4 + q;
                int p = prb + jf * 16 + lr;
                float* yp = y + (size_t)(bl0 + t) * D_INNER + h * HEADDIM + p;
                *yp = fmaf(__expf(lcs[t]), yi[i][jf][q], *yp);
            }
}

// ---------------- K4: yz = y*silu(z); RMSNorm(yz)*norm_w -> bf16 ------------
__global__ __launch_bounds__(256) void gate_rmsnorm(const float* __restrict__ y,
                                                    const short* __restrict__ zxs,
                                                    const float* __restrict__ nw,
                                                    short* __restrict__ yzb) {
    int bl = blockIdx.x;
    const float* yr = y + (size_t)bl * D_INNER;
    const short* zr = zxs + (size_t)bl * D_IN_PROJ;   // z = first 2048 cols, bf16
    int e0 = threadIdx.x * 8;

    float4 y0 = *(const float4*)(yr + e0);
    float4 y1 = *(const float4*)(yr + e0 + 4);
    s16x8 zv = *(const s16x8*)(zr + e0);

    float v[8];
    float yy[8] = {y0.x, y0.y, y0.z, y0.w, y1.x, y1.y, y1.z, y1.w};
    float ss = 0.f;
    #pragma unroll
    for (int i = 0; i < 8; ++i) {
        float zz = bf2f(zv[i]);
        v[i] = yy[i] * zz * sigmoidf_(zz);
        ss = fmaf(v[i], v[i], ss);
    }
    ss += __shfl_xor(ss, 1);  ss += __shfl_xor(ss, 2);  ss += __shfl_xor(ss, 4);
    ss += __shfl_xor(ss, 8);  ss += __shfl_xor(ss, 16); ss += __shfl_xor(ss, 32);
    __shared__ float red[4];
    int wave = threadIdx.x >> 6;
    if ((threadIdx.x & 63) == 0) red[wave] = ss;
    __syncthreads();
    ss = red[0] + red[1] + red[2] + red[3];

    float scale = rsqrtf(ss * (1.f / D_INNER) + EPSF);
    s16x8 o;
    #pragma unroll
    for (int i = 0; i < 8; ++i) o[i] = f2bf(v[i] * scale * nw[e0 + i]);
    *(s16x8*)(yzb + (size_t)bl * D_INNER + e0) = o;
}

// ---------------- launcher ----------------
extern "C" void kernel_launch(void* const* d_in, const int* in_sizes, int n_in,
                              void* d_out, int out_size, void* d_ws, size_t ws_size,
                              hipStream_t stream) {
    const float* x        = (const float*)d_in[0];
    const float* in_w     = (const float*)d_in[1];
    const float* conv_w   = (const float*)d_in[2];
    const float* conv_b   = (const float*)d_in[3];
    const float* dt_bias  = (const float*)d_in[4];
    const float* A_log    = (const float*)d_in[5];
    const float* Dp       = (const float*)d_in[6];
    const float* norm_w   = (const float*)d_in[7];
    const float* out_w    = (const float*)d_in[8];
    float* out            = (float*)d_out;

    float* ws   = (float*)d_ws;
    short* zxs  = (short*)(ws + OFF_ZX);             // bf16 zxbcdt
    float* xBC  = ws + OFF_XBC;
    float* dt   = ws + OFF_DT;
    float* y    = ws + OFF_Y;
    short* sb   = (short*)(ws + FLOAT_END);
    short* xb   = sb + SOFF_XB;
    short* w1b  = sb + SOFF_W1B;
    short* w2b  = sb + SOFF_W2B;
    short* yzb  = sb + SOFF_YZB;
    short* hd16  = xb;                                // overlay, post-K1
    float* datot = (float*)(hd16 + HD_SHORTS);

    // K0: fp32 -> bf16
    {
        int n = NROWS * DM;
        cvt_bf16<<<n / 4 / 256, 256, 0, stream>>>(x, xb, n, n);
        int ns = D_IN_PROJ * DM, nd = NPAD_IN * DM;
        cvt_bf16<<<nd / 4 / 256, 256, 0, stream>>>(in_w, w1b, ns, nd);
        int n2 = DM * D_INNER;
        cvt_bf16<<<n2 / 4 / 256, 256, 0, stream>>>(out_w, w2b, n2, n2);
    }
    // K1: zxbcdt = x @ in_proj_w^T  -> bf16 (grid 35*32=1120, %8==0)
    gemm_mfma<short><<<(NPAD_IN / 128) * (NROWS / 128), 256, 0, stream>>>(
        xb, w1b, zxs, DM, D_IN_PROJ, NPAD_IN / 128);
    // K2: conv + silu
    {
        int total = NROWS * CONV_DIM;
        conv_silu<<<(total + 255) / 256, 256, 0, stream>>>(zxs, conv_w, conv_b, xBC);
    }
    // K2b: dt
    {
        int total = NROWS * NHEADS;
        dt_da<<<(total + 255) / 256, 256, 0, stream>>>(zxs, dt_bias, dt);
    }
    // K3: chunked MFMA scan
    ssm_mfma_a<<<BATCH * NCHUNK * NHEADS, 1024, 0, stream>>>(xBC, dt, A_log, Dp, y, hd16, datot);
    ssm_state_b<<<BH, 512, 0, stream>>>(hd16, datot);
    ssm_mfma_c<<<BATCH * NCHUNK * NHEADS, 512, 0, stream>>>(xBC, dt, A_log, hd16, y);
    // K4: gate + rmsnorm -> bf16
    gate_rmsnorm<<<NROWS, 256, 0, stream>>>(y, zxs, norm_w, yzb);
    // K5: out = yz @ out_proj_w^T -> fp32 (grid 8*32=256, %8==0)
    gemm_mfma<float><<<(DM / 128) * (NROWS / 128), 256, 0, stream>>>(
        yzb, w2b, out, D_INNER, DM, DM / 128);
}

// Round 10
// 292.143 us; speedup vs baseline: 2.6593x; 1.0580x over previous
//
#include <hip/hip_runtime.h>
#include <hip/hip_bf16.h>

#define DM        1024
#define D_INNER   2048
#define NHEADS    32
#define HEADDIM   64
#define DSTATE    128
#define DCONV     4
#define CONV_DIM  (D_INNER + 2*DSTATE)            // 2304
#define D_IN_PROJ (2*D_INNER + 2*DSTATE + NHEADS) // 4384
#define NPAD_IN   4480                            // 35*128, padded N for K1
#define BATCH     4
#define SEQ       1024
#define NROWS     (BATCH*SEQ)                     // 4096
#define EPSF      1e-5f
#define CHUNK     128
#define NCHUNK    (SEQ/CHUNK)                     // 8
#define BH        (BATCH*NHEADS)                  // 128

// ---------------- workspace layout ----------------
// zx slot is fp32-sized; bf16 zxs uses its first half, K5 partials the second.
#define OFF_ZX   ((size_t)0)                        // [4096][4384] bf16 zxbcdt
#define OFF_PART (OFF_ZX + (size_t)NROWS*D_IN_PROJ/2) // [2][4096][1024] f32 partials
#define OFF_XBC  ((size_t)(NROWS)*D_IN_PROJ)        // [4096][2304] bf16 (half-used slot)
#define OFF_DT   (OFF_XBC + (size_t)NROWS*CONV_DIM) // [4096][32]
#define OFF_DA   (OFF_DT  + (size_t)NROWS*NHEADS)   // [4096][32]
#define OFF_Y    (OFF_DA  + (size_t)NROWS*NHEADS)   // [4096][2048] fp32
#define FLOAT_END (OFF_Y + (size_t)NROWS*D_INNER)
// bf16 (short) region
#define SOFF_XB   ((size_t)0)                           // [4096][1024]  dead after K1
#define SOFF_W1B  (SOFF_XB  + (size_t)NROWS*DM)         // [4480][1024]  dead after K1
#define SOFF_W2B  (SOFF_W1B + (size_t)NPAD_IN*DM)       // [1024][2048]
#define SOFF_YZB  (SOFF_W2B + (size_t)DM*D_INNER)       // [4096][2048]
#define HD_SHORTS ((size_t)NCHUNK*BH*HEADDIM*DSTATE)

typedef float  vf4   __attribute__((ext_vector_type(4)));
typedef short  s16x8 __attribute__((ext_vector_type(8)));
typedef short  s16x4 __attribute__((ext_vector_type(4)));
typedef __bf16 bf16x8 __attribute__((ext_vector_type(8)));

__device__ __forceinline__ float sigmoidf_(float x) { return 1.f / (1.f + expf(-x)); }

__device__ __forceinline__ short f2bf(float f) {
    unsigned u = __builtin_bit_cast(unsigned, f);
    u += 0x7fffu + ((u >> 16) & 1u);          // RNE
    return (short)(u >> 16);
}
__device__ __forceinline__ float bf2f(short s) {
    unsigned u = ((unsigned)(unsigned short)s) << 16;
    return __builtin_bit_cast(float, u);
}
__device__ __forceinline__ bf16x8 as_bf(s16x8 v) { return __builtin_bit_cast(bf16x8, v); }
#define MFMA(a,b,c) __builtin_amdgcn_mfma_f32_16x16x32_bf16(as_bf(a), as_bf(b), (c), 0, 0, 0)

template <typename T> __device__ __forceinline__ T cvt_out(float v);
template <> __device__ __forceinline__ float cvt_out<float>(float v) { return v; }
template <> __device__ __forceinline__ short cvt_out<short>(float v) { return f2bf(v); }

__device__ __forceinline__ void gload16(const short* g, short* l) {
    __builtin_amdgcn_global_load_lds(
        (const __attribute__((address_space(1))) unsigned int*)g,
        (__attribute__((address_space(3))) unsigned int*)l, 16, 0, 0);
}

// swizzled [rows][128] bf16 tile: 16B chunk c of row r stored at chunk (c ^ (r&7))
__device__ __forceinline__ int swz_idx(int r, int kc) {
    return r * 128 + (((kc) ^ (r & 7)) << 3);
}
// swizzled [rows][64] bf16 tile
__device__ __forceinline__ int swz64_idx(int r, int c) {
    return r * 64 + (((c) ^ (r & 7)) << 3);
}

// ---------------- K0: fp32 -> bf16 convert ----------------
__global__ __launch_bounds__(256) void cvt_bf16(const float* __restrict__ src,
                                                short* __restrict__ dst,
                                                int n_src, int n_dst) {
    int i = (blockIdx.x * 256 + threadIdx.x) * 4;
    if (i >= n_dst) return;
    s16x4 o;
    if (i + 3 < n_src) {
        float4 v = *(const float4*)(src + i);
        o[0] = f2bf(v.x); o[1] = f2bf(v.y); o[2] = f2bf(v.z); o[3] = f2bf(v.w);
    } else {
        #pragma unroll
        for (int j = 0; j < 4; ++j) o[j] = (i + j < n_src) ? f2bf(src[i + j]) : (short)0;
    }
    *(s16x4*)(dst + i) = o;
}

// ------- MFMA GEMM, flat grid + XCD-bijective swizzle + optional split-K -----
// grid.x must be % 8. C[+kz*cstride][M][Nout] = A[M][Kfull](koff..) * B^T
template <typename OutT>
__global__ __launch_bounds__(256) void gemm_mfma(const short* __restrict__ A,
                                                 const short* __restrict__ B,
                                                 OutT* __restrict__ C,
                                                 int Ksplit, int Kfull, int Nout,
                                                 int nbx, int ntiles, size_t cstride) {
    __shared__ short smem[16384];
    const int tid = threadIdx.x;
    const int cpx = gridDim.x >> 3;
    const int wgid = (blockIdx.x & 7) * cpx + (blockIdx.x >> 3);
    const int kz = wgid / ntiles, t2 = wgid % ntiles;
    const int bm = (t2 / nbx) * 128, bn = (t2 % nbx) * 128;
    const int koff = kz * Ksplit;
    const int lane = tid & 63, lr = lane & 15, lg = lane >> 4;
    const int w = tid >> 6, wm = w >> 1, wn = w & 1;

    const short* ga[4]; const short* gb[4];
    short* la[4]; short* lb[4];
    #pragma unroll
    for (int t = 0; t < 4; ++t) {
        int s = t * 256 + tid;
        int r = s >> 3;
        int c = (s & 7) ^ (r & 7);
        ga[t] = A + (size_t)(bm + r) * Kfull + c * 8;
        gb[t] = B + (size_t)(bn + r) * Kfull + c * 8;
        la[t] = &smem[s * 8];
        lb[t] = &smem[8192 + s * 8];
    }

    vf4 acc[4][4] = {};

    for (int k0 = koff; k0 < koff + Ksplit; k0 += 64) {
        __syncthreads();
        #pragma unroll
        for (int t = 0; t < 4; ++t) gload16(ga[t] + k0, la[t]);
        #pragma unroll
        for (int t = 0; t < 4; ++t) gload16(gb[t] + k0, lb[t]);
        __syncthreads();
        #pragma unroll
        for (int kk = 0; kk < 2; ++kk) {
            const int co = ((kk * 4 + lg) ^ (lr & 7)) * 8;
            s16x8 av[4], bv[4];
            #pragma unroll
            for (int f = 0; f < 4; ++f) {
                av[f] = *(const s16x8*)&smem[(wm * 64 + f * 16 + lr) * 64 + co];
                bv[f] = *(const s16x8*)&smem[8192 + (wn * 64 + f * 16 + lr) * 64 + co];
            }
            #pragma unroll
            for (int i = 0; i < 4; ++i)
                #pragma unroll
                for (int j = 0; j < 4; ++j)
                    acc[i][j] = MFMA(av[i], bv[j], acc[i][j]);
        }
    }

    #pragma unroll
    for (int i = 0; i < 4; ++i) {
        int row = bm + wm * 64 + i * 16 + lg * 4;
        #pragma unroll
        for (int j = 0; j < 4; ++j) {
            int col = bn + wn * 64 + j * 16 + lr;
            if (col < Nout) {
                OutT* cp = C + cstride * kz + (size_t)row * Nout + col;
                #pragma unroll
                for (int q = 0; q < 4; ++q) cp[(size_t)q * Nout] = cvt_out<OutT>(acc[i][j][q]);
            }
        }
    }
}

// ---------------- split-K reduce: out = p0 + p1 ----------------
__global__ __launch_bounds__(256) void reduce_add(const float* __restrict__ p,
                                                  float* __restrict__ out, int n) {
    int i = (blockIdx.x * 256 + threadIdx.x) * 4;
    if (i >= n) return;
    float4 a = *(const float4*)(p + i);
    float4 b = *(const float4*)(p + n + i);
    float4 o = make_float4(a.x + b.x, a.y + b.y, a.z + b.z, a.w + b.w);
    *(float4*)(out + i) = o;
}

// ---------------- K2: causal depthwise conv(4) + silu (bf16 in/out) ---------
__global__ __launch_bounds__(256) void conv_silu(const short* __restrict__ zx,
                                                 const float* __restrict__ cw,
                                                 const float* __restrict__ cb,
                                                 short* __restrict__ xBCs) {
    int idx = blockIdx.x * 256 + threadIdx.x;
    if (idx >= NROWS * CONV_DIM) return;
    int c  = idx % CONV_DIM;
    int bl = idx / CONV_DIM;
    int b  = bl / SEQ;
    int l  = bl % SEQ;

    float w0 = cw[c*4+0], w1 = cw[c*4+1], w2 = cw[c*4+2], w3 = cw[c*4+3];
    const short* base = zx + (size_t)b * SEQ * D_IN_PROJ + D_INNER + c;

    float acc = cb[c];
    if (l >= 3) acc = fmaf(bf2f(base[(size_t)(l-3) * D_IN_PROJ]), w0, acc);
    if (l >= 2) acc = fmaf(bf2f(base[(size_t)(l-2) * D_IN_PROJ]), w1, acc);
    if (l >= 1) acc = fmaf(bf2f(base[(size_t)(l-1) * D_IN_PROJ]), w2, acc);
    acc = fmaf(bf2f(base[(size_t)l * D_IN_PROJ]), w3, acc);

    xBCs[idx] = f2bf(acc * sigmoidf_(acc));
}

// ---------------- K2b: dt = softplus(dt_raw + bias) ----------------
__global__ __launch_bounds__(256) void dt_da(const short* __restrict__ zx,
                                             const float* __restrict__ dt_bias,
                                             float* __restrict__ dt) {
    int idx = blockIdx.x * 256 + threadIdx.x;
    if (idx >= NROWS * NHEADS) return;
    int h  = idx & (NHEADS - 1);
    int bl = idx >> 5;
    float u = bf2f(zx[(size_t)bl * D_IN_PROJ + D_INNER + CONV_DIM + h]) + dt_bias[h];
    float d = (u > 20.f) ? u : log1pf(expf(u));
    dt[idx] = d;
}

// ---------------- K3a: chunked MFMA scan, intra-chunk ----------------
#define L_CT 0
#define L_XT 0
#define L_BT 16384
#define L_BW 32768
#define L_XN 49152
__global__ __launch_bounds__(1024) void ssm_mfma_a(const short* __restrict__ xBCs,
                                                   const float* __restrict__ dt,
                                                   const float* __restrict__ A_log,
                                                   const float* __restrict__ Dp,
                                                   float* __restrict__ y,
                                                   short* __restrict__ hd16,
                                                   float* __restrict__ datot) {
    __shared__ short sm[57344];
    __shared__ float dtl[128], lcs[128];
    int blk = (blockIdx.x & 7) * (gridDim.x >> 3) + (blockIdx.x >> 3);
    int h = blk & 31, k = (blk >> 5) & (NCHUNK - 1), b = blk >> 8;
    int tid = threadIdx.x, w = tid >> 6, lane = tid & 63, lr = lane & 15, lg = lane >> 4;
    int bl0 = b * SEQ + k * CHUNK;
    const short* xrow = xBCs + (size_t)bl0 * CONV_DIM;

    // P1: stage C, B ([128][128]) and XN=[j][p] ([128][64]) via global_load_lds,
    // pre-swizzled global source, linear LDS dest (rule 21; same as gemm_mfma).
    #pragma unroll
    for (int t = 0; t < 2; ++t) {
        int s = t * 1024 + tid, r = s >> 4, c = (s & 15) ^ (r & 7);
        gload16(xrow + (size_t)r * CONV_DIM + (D_INNER + DSTATE) + c * 8, &sm[L_CT + s * 8]);
    }
    #pragma unroll
    for (int t = 0; t < 2; ++t) {
        int s = t * 1024 + tid, r = s >> 4, c = (s & 15) ^ (r & 7);
        gload16(xrow + (size_t)r * CONV_DIM + D_INNER + c * 8, &sm[L_BT + s * 8]);
    }
    {
        int r = tid >> 3, c = (tid & 7) ^ (r & 7);
        gload16(xrow + (size_t)r * CONV_DIM + h * HEADDIM + c * 8, &sm[L_XN + tid * 8]);
    }
    // P0: dt slice (overlaps with in-flight loads)
    if (tid < 128) dtl[tid] = dt[(size_t)(bl0 + tid) * NHEADS + h];
    __syncthreads();            // drains vmcnt: tiles + dtl visible

    // P2 (wave 0): lc = A * inclusive-cumsum(dt) — overlaps other waves' G
    float Ah = -__expf(A_log[h]);
    if (w == 0) {
        float a = dtl[lane], bb = dtl[64 + lane];
        #pragma unroll
        for (int d = 1; d < 64; d <<= 1) { float v = __shfl_up(a, d);  if (lane >= d) a  += v; }
        #pragma unroll
        for (int d = 1; d < 64; d <<= 1) { float v = __shfl_up(bb, d); if (lane >= d) bb += v; }
        bb += __shfl(a, 63);
        lcs[lane]      = Ah * a;
        lcs[64 + lane] = Ah * bb;
        if (lane == 63) datot[k * BH + b * NHEADS + h] = __expf(Ah * bb);
    }

    // G = C @ B^T : 16 waves, each 16 rows x 64 cols
    vf4 g[4] = {};
    const int rb = (w & 7) * 16, cb = (w >> 3) * 64;
    #pragma unroll
    for (int ks = 0; ks < 4; ++ks) {
        int kc = ks * 4 + lg;
        s16x8 av = *(const s16x8*)&sm[L_CT + swz_idx(rb + lr, kc)];
        #pragma unroll
        for (int jf = 0; jf < 4; ++jf) {
            s16x8 bv = *(const s16x8*)&sm[L_BT + swz_idx(cb + jf * 16 + lr, kc)];
            g[jf] = MFMA(av, bv, g[jf]);
        }
    }
    __syncthreads();    // G done reading CT/BT; lcs ready

    float lcLast = lcs[127];

    // P3a: XT[p][j] = dt_j * X[j][p]  (reads XN cols: lanes span p -> 2-way free)
    {
        int p = tid & 63, c2 = tid >> 6;
        s16x8 o;
        #pragma unroll
        for (int jj = 0; jj < 8; ++jj) {
            int j = c2 * 8 + jj;
            float xv = bf2f(sm[L_XN + swz64_idx(j, p >> 3) + (p & 7)]);
            o[jj] = f2bf(dtl[j] * xv);
        }
        *(s16x8*)&sm[L_XT + swz_idx(p, c2)] = o;
    }
    // P3b: BW[n][j] = B[j][n]*exp(lcLast-lc_j)  (lanes span n -> 2-way free)
    for (int s = tid; s < 2048; s += 1024) {
        int n = s & 127, c = s >> 7;
        s16x8 o;
        #pragma unroll
        for (int jj = 0; jj < 8; ++jj) {
            int j = c * 8 + jj;
            float bv = bf2f(sm[L_BT + swz_idx(j, n >> 3) + (n & 7)]);
            o[jj] = f2bf(bv * __expf(lcLast - lcs[j]));
        }
        *(s16x8*)&sm[L_BW + swz_idx(n, c)] = o;
    }
    __syncthreads();

    // P4: write M (masked, decayed) over B region
    #pragma unroll
    for (int jf = 0; jf < 4; ++jf)
        #pragma unroll
        for (int q = 0; q < 4; ++q) {
            int t = rb + lg * 4 + q;
            int j = cb + jf * 16 + lr;
            float v = (j <= t) ? g[jf][q] * __expf(lcs[t] - lcs[j]) : 0.f;
            sm[L_BT + swz_idx(t, j >> 3) + (j & 7)] = f2bf(v);
        }
    __syncthreads();

    // P5: Y_intra = M @ XT ; h_delta = XT @ BW
    vf4 yi[2] = {};
    vf4 hdl[2] = {};
    const int rb2 = (w & 7) * 16, prb = (w >> 3) * 32;
    const int hrb = (w & 3) * 16, hcb = (w >> 2) * 32;
    #pragma unroll
    for (int ks = 0; ks < 4; ++ks) {
        int kc = ks * 4 + lg;
        s16x8 am = *(const s16x8*)&sm[L_BT + swz_idx(rb2 + lr, kc)];
        s16x8 ax = *(const s16x8*)&sm[L_XT + swz_idx(hrb + lr, kc)];
        #pragma unroll
        for (int jf = 0; jf < 2; ++jf) {
            s16x8 bx = *(const s16x8*)&sm[L_XT + swz_idx(prb + jf * 16 + lr, kc)];
            s16x8 bw = *(const s16x8*)&sm[L_BW + swz_idx(hcb + jf * 16 + lr, kc)];
            yi[jf]  = MFMA(am, bx, yi[jf]);
            hdl[jf] = MFMA(ax, bw, hdl[jf]);
        }
    }

    // epilogue: y = Y_intra + D*x
    float Dh = Dp[h];
    #pragma unroll
    for (int jf = 0; jf < 2; ++jf)
        #pragma unroll
        for (int q = 0; q < 4; ++q) {
            int t = rb2 + lg * 4 + q;
            int p = prb + jf * 16 + lr;
            float xv = bf2f(xrow[(size_t)t * CONV_DIM + h * HEADDIM + p]);
            y[(size_t)(bl0 + t) * D_INNER + h * HEADDIM + p] = yi[jf][q] + Dh * xv;
        }
    // epilogue: h_delta -> hd16 [k][bh][p][n] bf16
    size_t hb = ((size_t)k * BH + b * NHEADS + h) * (HEADDIM * DSTATE);
    #pragma unroll
    for (int jf = 0; jf < 2; ++jf)
        #pragma unroll
        for (int q = 0; q < 4; ++q) {
            int p = hrb + lg * 4 + q;
            int n = hcb + jf * 16 + lr;
            hd16[hb + p * DSTATE + n] = f2bf(hdl[jf][q]);
        }
}

// ---------------- K3b: sequential chunk-state combine (in place) -----------
__global__ __launch_bounds__(512) void ssm_state_b(short* __restrict__ hd16,
                                                   const float* __restrict__ datot) {
    int bh = blockIdx.x;
    int base = threadIdx.x * 16;
    float hs[16];
    #pragma unroll
    for (int i = 0; i < 16; ++i) hs[i] = 0.f;
    #pragma unroll
    for (int k = 0; k < NCHUNK; ++k) {
        size_t off = ((size_t)k * BH + bh) * (HEADDIM * DSTATE) + base;
        float da = datot[k * BH + bh];
        s16x8 d0 = *(const s16x8*)&hd16[off], d1 = *(const s16x8*)&hd16[off + 8];
        s16x8 o0, o1;
        #pragma unroll
        for (int i = 0; i < 8; ++i) { o0[i] = f2bf(hs[i]); o1[i] = f2bf(hs[8 + i]); }
        *(s16x8*)&hd16[off] = o0; *(s16x8*)&hd16[off + 8] = o1;
        #pragma unroll
        for (int i = 0; i < 8; ++i) {
            hs[i]     = fmaf(da, hs[i],     bf2f(d0[i]));
            hs[8 + i] = fmaf(da, hs[8 + i], bf2f(d1[i]));
        }
    }
}

// ---------------- K3c: Y_inter += exp(lc_t) * C @ h_in ----------------
__global__ __launch_bounds__(512) void ssm_mfma_c(const short* __restrict__ xBCs,
                                                  const float* __restrict__ dt,
                                                  const float* __restrict__ A_log,
                                                  const short* __restrict__ hd16,
                                                  float* __restrict__ y) {
    int blk = (blockIdx.x & 7) * (gridDim.x >> 3) + (blockIdx.x >> 3);
    int h = blk & 31, k = (blk >> 5) & (NCHUNK - 1), b = blk >> 8;
    if (k == 0) return;
    __shared__ short sm[16384];
    __shared__ float dtl[128], lcs[128];
    int tid = threadIdx.x, w = tid >> 6, lane = tid & 63, lr = lane & 15, lg = lane >> 4;
    int bl0 = b * SEQ + k * CHUNK;
    const short* xrow = xBCs + (size_t)bl0 * CONV_DIM;

    // stage C via global_load_lds, pre-swizzled source
    #pragma unroll
    for (int t = 0; t < 4; ++t) {
        int s = t * 512 + tid, r = s >> 4, c = (s & 15) ^ (r & 7);
        gload16(xrow + (size_t)r * CONV_DIM + (D_INNER + DSTATE) + c * 8, &sm[s * 8]);
    }
    if (tid < 128) dtl[tid] = dt[(size_t)(bl0 + tid) * NHEADS + h];
    float Ah = -__expf(A_log[h]);
    __syncthreads();
    if (w == 0) {
        float a = dtl[lane], bb = dtl[64 + lane];
        #pragma unroll
        for (int d = 1; d < 64; d <<= 1) { float v = __shfl_up(a, d);  if (lane >= d) a  += v; }
        #pragma unroll
        for (int d = 1; d < 64; d <<= 1) { float v = __shfl_up(bb, d); if (lane >= d) bb += v; }
        bb += __shfl(a, 63);
        lcs[lane]      = Ah * a;
        lcs[64 + lane] = Ah * bb;
    }
    __syncthreads();

    const short* hin = hd16 + ((size_t)k * BH + b * NHEADS + h) * (HEADDIM * DSTATE);
    vf4 yi[2][2] = {};
    const int rb = (w & 3) * 32, prb = (w >> 2) * 32;
    #pragma unroll
    for (int ks = 0; ks < 4; ++ks) {
        int kc = ks * 4 + lg;
        s16x8 av[2], bv[2];
        #pragma unroll
        for (int i = 0; i < 2; ++i)  { int r = rb + i * 16 + lr; av[i] = *(const s16x8*)&sm[swz_idx(r, kc)]; }
        #pragma unroll
        for (int jf = 0; jf < 2; ++jf){
            int p = prb + jf * 16 + lr;
            bv[jf] = *(const s16x8*)&hin[p * DSTATE + ks * 32 + lg * 8];
        }
        #pragma unroll
        for (int i = 0; i < 2; ++i)
            #pragma unroll
            for (int jf = 0; jf < 2; ++jf)
                yi[i][jf] = MFMA(av[i], bv[jf], yi[i][jf]);
    }
    #pragma unroll
    for (int i = 0; i < 2; ++i)
        #pragma unroll
        for (int jf = 0; jf < 2; ++jf)
            #pragma unroll
            for (int q = 0; q < 4; ++q) {
                int t = rb + i * 16 + lg * 4 + q;
                int p = prb + jf * 16 + lr;
                float* yp = y + (size_t)(bl0 + t) * D_INNER + h * HEADDIM + p;
                *yp = fmaf(__expf(lcs[t]), yi[i][jf][q], *yp);
            }
}

// ---------------- K4: yz = y*silu(z); RMSNorm(yz)*norm_w -> bf16 ------------
__global__ __launch_bounds__(256) void gate_rmsnorm(const float* __restrict__ y,
                                                    const short* __restrict__ zxs,
                                                    const float* __restrict__ nw,
                                                    short* __restrict__ yzb) {
    int bl = blockIdx.x;
    const float* yr = y + (size_t)bl * D_INNER;
    const short* zr = zxs + (size_t)bl * D_IN_PROJ;   // z = first 2048 cols, bf16
    int e0 = threadIdx.x * 8;

    float4 y0 = *(const float4*)(yr + e0);
    float4 y1 = *(const float4*)(yr + e0 + 4);
    s16x8 zv = *(const s16x8*)(zr + e0);

    float v[8];
    float yy[8] = {y0.x, y0.y, y0.z, y0.w, y1.x, y1.y, y1.z, y1.w};
    float ss = 0.f;
    #pragma unroll
    for (int i = 0; i < 8; ++i) {
        float zz = bf2f(zv[i]);
        v[i] = yy[i] * zz * sigmoidf_(zz);
        ss = fmaf(v[i], v[i], ss);
    }
    ss += __shfl_xor(ss, 1);  ss += __shfl_xor(ss, 2);  ss += __shfl_xor(ss, 4);
    ss += __shfl_xor(ss, 8);  ss += __shfl_xor(ss, 16); ss += __shfl_xor(ss, 32);
    __shared__ float red[4];
    int wave = threadIdx.x >> 6;
    if ((threadIdx.x & 63) == 0) red[wave] = ss;
    __syncthreads();
    ss = red[0] + red[1] + red[2] + red[3];

    float scale = rsqrtf(ss * (1.f / D_INNER) + EPSF);
    s16x8 o;
    #pragma unroll
    for (int i = 0; i < 8; ++i) o[i] = f2bf(v[i] * scale * nw[e0 + i]);
    *(s16x8*)(yzb + (size_t)bl * D_INNER + e0) = o;
}

// ---------------- launcher ----------------
extern "C" void kernel_launch(void* const* d_in, const int* in_sizes, int n_in,
                              void* d_out, int out_size, void* d_ws, size_t ws_size,
                              hipStream_t stream) {
    const float* x        = (const float*)d_in[0];
    const float* in_w     = (const float*)d_in[1];
    const float* conv_w   = (const float*)d_in[2];
    const float* conv_b   = (const float*)d_in[3];
    const float* dt_bias  = (const float*)d_in[4];
    const float* A_log    = (const float*)d_in[5];
    const float* Dp       = (const float*)d_in[6];
    const float* norm_w   = (const float*)d_in[7];
    const float* out_w    = (const float*)d_in[8];
    float* out            = (float*)d_out;

    float* ws   = (float*)d_ws;
    short* zxs  = (short*)(ws + OFF_ZX);             // bf16 zxbcdt
    float* part = ws + OFF_PART;                     // K5 split-K partials
    short* xBCs = (short*)(ws + OFF_XBC);            // bf16 conv output
    float* dt   = ws + OFF_DT;
    float* y    = ws + OFF_Y;
    short* sb   = (short*)(ws + FLOAT_END);
    short* xb   = sb + SOFF_XB;
    short* w1b  = sb + SOFF_W1B;
    short* w2b  = sb + SOFF_W2B;
    short* yzb  = sb + SOFF_YZB;
    short* hd16  = xb;                                // overlay, post-K1
    float* datot = (float*)(hd16 + HD_SHORTS);

    // K0: fp32 -> bf16
    {
        int n = NROWS * DM;
        cvt_bf16<<<n / 4 / 256, 256, 0, stream>>>(x, xb, n, n);
        int ns = D_IN_PROJ * DM, nd = NPAD_IN * DM;
        cvt_bf16<<<nd / 4 / 256, 256, 0, stream>>>(in_w, w1b, ns, nd);
        int n2 = DM * D_INNER;
        cvt_bf16<<<n2 / 4 / 256, 256, 0, stream>>>(out_w, w2b, n2, n2);
    }
    // K1: zxbcdt = x @ in_proj_w^T -> bf16 (grid 1120, no split)
    gemm_mfma<short><<<(NPAD_IN / 128) * (NROWS / 128), 256, 0, stream>>>(
        xb, w1b, zxs, DM, DM, D_IN_PROJ, NPAD_IN / 128, (NPAD_IN / 128) * (NROWS / 128), 0);
    // K2: conv + silu -> bf16
    {
        int total = NROWS * CONV_DIM;
        conv_silu<<<(total + 255) / 256, 256, 0, stream>>>(zxs, conv_w, conv_b, xBCs);
    }
    // K2b: dt
    {
        int total = NROWS * NHEADS;
        dt_da<<<(total + 255) / 256, 256, 0, stream>>>(zxs, dt_bias, dt);
    }
    // K3: chunked MFMA scan
    ssm_mfma_a<<<BATCH * NCHUNK * NHEADS, 1024, 0, stream>>>(xBCs, dt, A_log, Dp, y, hd16, datot);
    ssm_state_b<<<BH, 512, 0, stream>>>(hd16, datot);
    ssm_mfma_c<<<BATCH * NCHUNK * NHEADS, 512, 0, stream>>>(xBCs, dt, A_log, hd16, y);
    // K4: gate + rmsnorm -> bf16
    gate_rmsnorm<<<NROWS, 256, 0, stream>>>(y, zxs, norm_w, yzb);
    // K5: out = yz @ out_proj_w^T, split-K=2 (grid 512 = 2 x 256 tiles)
    gemm_mfma<float><<<512, 256, 0, stream>>>(
        yzb, w2b, part, D_INNER / 2, D_INNER, DM, DM / 128, 256, (size_t)NROWS * DM);
    reduce_add<<<NROWS * DM / 4 / 256, 256, 0, stream>>>(part, out, NROWS * DM);
}